// Round 3
// baseline (3939.474 us; speedup 1.0000x reference)
//
#include <hip/hip_runtime.h>
#include <hip/hip_bf16.h>

typedef __hip_bfloat16 bf16;

#define NT 262144
#define ND 262144
#define EDT 2097152
#define ETT 1048576

// ---- dual-dtype load/store: isbf==1 -> bf16, else fp32 ----
__device__ __forceinline__ float ldf(const void* p, long i, int isbf){
    if (isbf) return __bfloat162float(((const bf16*)p)[i]);
    return ((const float*)p)[i];
}
__device__ __forceinline__ void stf(void* p, int i, float v, int isbf){
    if (isbf) ((bf16*)p)[i] = __float2bfloat16(v);
    else      ((float*)p)[i] = v;
}
__device__ __forceinline__ float fin(float x){
    return (x==x && x>-3e38f && x<3e38f) ? x : 0.f;
}

// ---- input dtype detection: sample low-16-bit exponent fields of x_tasks ----
// bf16-packed N(0,1): low half is a bf16 value, exp in [116,134] ~99.9%.
// fp32: low half is random mantissa bits, ~7% hit rate. Threshold at 50%.
__global__ void detect_kernel(const unsigned* __restrict__ raw, int* __restrict__ flag){
    __shared__ int cnt;
    if (threadIdx.x==0) cnt = 0;
    __syncthreads();
    int c = 0;
    for (int i = threadIdx.x; i < 2048; i += 256){
        unsigned w = raw[i];
        unsigned e = (w >> 7) & 0xFFu;
        if (e >= 116u && e <= 134u) c++;
    }
    atomicAdd(&cnt, c);
    __syncthreads();
    if (threadIdx.x==0) *flag = (cnt > 1024) ? 1 : 0;
}

// ---------------- stems ----------------
template<int F>
__global__ __launch_bounds__(256) void stem_kernel(
    const void* __restrict__ x, const void* __restrict__ W, const void* __restrict__ bias,
    const void* __restrict__ lng, const void* __restrict__ lnb, float* __restrict__ out,
    const int* __restrict__ flag)
{
    int isbf = *flag;
    __shared__ float sW[F*16], sb[16], sg[16], sbt[16];
    int t = threadIdx.x;
    if (t < F*16) sW[t] = ldf(W, t, isbf);
    if (t < 16){ sb[t]=ldf(bias,t,isbf); sg[t]=ldf(lng,t,isbf); sbt[t]=ldf(lnb,t,isbf); }
    __syncthreads();
    long i = blockIdx.x*256 + t;
    float f[F];
    #pragma unroll
    for (int k=0;k<F;k++) f[k] = ldf(x, i*F+k, isbf);
    float h[16];
    #pragma unroll
    for (int c=0;c<16;c++){
        float a = sb[c];
        #pragma unroll
        for (int k=0;k<F;k++) a += f[k]*sW[k*16+c];
        h[c]=a;
    }
    float mu=0.f;
    #pragma unroll
    for (int c=0;c<16;c++) mu += h[c];
    mu *= (1.f/16.f);
    float var=0.f;
    #pragma unroll
    for (int c=0;c<16;c++){ float d=h[c]-mu; var += d*d; }
    var *= (1.f/16.f);
    float inv = rsqrtf(var + 1e-5f);
    #pragma unroll
    for (int c=0;c<16;c++){
        float y = sg[c]*(h[c]-mu)*inv + sbt[c];
        out[i*16+c] = fin((y>0.f) ? y : 0.01f*y);
    }
}

// data stem fused with @Wl -> xl[ND,32]
__global__ __launch_bounds__(256) void stem_data_transform_kernel(
    const void* __restrict__ x, const void* __restrict__ W, const void* __restrict__ bias,
    const void* __restrict__ lng, const void* __restrict__ lnb,
    const void* __restrict__ Wl, float* __restrict__ xl,
    const int* __restrict__ flag)
{
    int isbf = *flag;
    __shared__ float sW[80], sb[16], sg[16], sbt[16], sWl[512];
    int t = threadIdx.x;
    if (t < 80) sW[t] = ldf(W, t, isbf);
    if (t < 16){ sb[t]=ldf(bias,t,isbf); sg[t]=ldf(lng,t,isbf); sbt[t]=ldf(lnb,t,isbf); }
    sWl[t]     = ldf(Wl, t,     isbf);
    sWl[t+256] = ldf(Wl, t+256, isbf);
    __syncthreads();
    long i = blockIdx.x*256 + t;
    float f[5];
    #pragma unroll
    for (int k=0;k<5;k++) f[k] = ldf(x, i*5+k, isbf);
    float h[16];
    #pragma unroll
    for (int c=0;c<16;c++){
        float a = sb[c];
        #pragma unroll
        for (int k=0;k<5;k++) a += f[k]*sW[k*16+c];
        h[c]=a;
    }
    float mu=0.f;
    #pragma unroll
    for (int c=0;c<16;c++) mu += h[c];
    mu *= (1.f/16.f);
    float var=0.f;
    #pragma unroll
    for (int c=0;c<16;c++){ float d=h[c]-mu; var += d*d; }
    var *= (1.f/16.f);
    float inv = rsqrtf(var + 1e-5f);
    float v[16];
    #pragma unroll
    for (int c=0;c<16;c++){
        float y = sg[c]*(h[c]-mu)*inv + sbt[c];
        v[c] = (y>0.f) ? y : 0.01f*y;
    }
    float o[32];
    #pragma unroll
    for (int c=0;c<32;c++) o[c]=0.f;
    #pragma unroll
    for (int k=0;k<16;k++){
        float xv=v[k];
        #pragma unroll
        for (int c=0;c<32;c++) o[c] += xv*sWl[k*32+c];
    }
    float4* op = (float4*)(xl + i*32);
    #pragma unroll
    for (int q=0;q<8;q++)
        op[q] = make_float4(fin(o[q*4]),fin(o[q*4+1]),fin(o[q*4+2]),fin(o[q*4+3]));
}

// 16 -> 32 transform (xl/xr)
__global__ __launch_bounds__(256) void transform_kernel(
    const float* __restrict__ x, const void* __restrict__ W, float* __restrict__ out,
    const int* __restrict__ flag)
{
    int isbf = *flag;
    __shared__ float sW[512];
    int t = threadIdx.x;
    sW[t]     = ldf(W, t,     isbf);
    sW[t+256] = ldf(W, t+256, isbf);
    __syncthreads();
    long i = blockIdx.x*256 + t;
    const float4* xp = (const float4*)(x + i*16);
    float4 x0=xp[0], x1=xp[1], x2=xp[2], x3=xp[3];
    float xi[16] = {x0.x,x0.y,x0.z,x0.w, x1.x,x1.y,x1.z,x1.w,
                    x2.x,x2.y,x2.z,x2.w, x3.x,x3.y,x3.z,x3.w};
    float o[32];
    #pragma unroll
    for (int c=0;c<32;c++) o[c]=0.f;
    #pragma unroll
    for (int k=0;k<16;k++){
        float xv=xi[k];
        #pragma unroll
        for (int c=0;c<32;c++) o[c] += xv*sW[k*32+c];
    }
    float4* op = (float4*)(out + i*32);
    #pragma unroll
    for (int q=0;q<8;q++)
        op[q] = make_float4(fin(o[q*4]),fin(o[q*4+1]),fin(o[q*4+2]),fin(o[q*4+3]));
}

// ---------------- fused edge pass: score -> exp -> atomic aggregation ----------------
__global__ __launch_bounds__(256) void edge_gat_kernel(
    const int* __restrict__ ei, const int* __restrict__ mask,
    const float* __restrict__ xl, const float* __restrict__ xr,
    const void* __restrict__ att,
    float* __restrict__ denom, float* __restrict__ num, int E,
    const int* __restrict__ flag)
{
    __shared__ float satt[32];
    if (threadIdx.x < 32) satt[threadIdx.x] = ldf(att, threadIdx.x, *flag);
    __syncthreads();
    int e = blockIdx.x*256 + threadIdx.x;
    if (e >= E) return;
    if (mask && mask[e]==0) return;
    long s = ei[e], d = ei[E+e];
    const float4* a4 = (const float4*)(xl + s*32);
    const float4* b4 = (const float4*)(xr + d*32);
    float xs[32];
    float sc0=0.f, sc1=0.f;
    #pragma unroll
    for (int q=0;q<8;q++){
        float4 a=a4[q], b=b4[q];
        xs[q*4]=a.x; xs[q*4+1]=a.y; xs[q*4+2]=a.z; xs[q*4+3]=a.w;
        float m0=a.x+b.x, m1=a.y+b.y, m2=a.z+b.z, m3=a.w+b.w;
        m0 = m0>0.f?m0:0.2f*m0; m1 = m1>0.f?m1:0.2f*m1;
        m2 = m2>0.f?m2:0.2f*m2; m3 = m3>0.f?m3:0.2f*m3;
        float p = m0*satt[q*4] + m1*satt[q*4+1] + m2*satt[q*4+2] + m3*satt[q*4+3];
        if (q < 4) sc0 += p; else sc1 += p;
    }
    float a0 = expf(fminf(fin(sc0), 60.f));
    float a1 = expf(fminf(fin(sc1), 60.f));
    atomicAdd(denom + d*2,     a0);
    atomicAdd(denom + d*2 + 1, a1);
    float* nd = num + d*32;
    #pragma unroll
    for (int c=0;c<16;c++){
        atomicAdd(nd + c,      a0*xs[c]);
        atomicAdd(nd + 16 + c, a1*xs[16+c]);
    }
}

__device__ __forceinline__ void ln_act16(const float* v, const float* g, const float* b, float* o){
    float mu=0.f;
    #pragma unroll
    for (int c=0;c<16;c++) mu += v[c];
    mu *= (1.f/16.f);
    float var=0.f;
    #pragma unroll
    for (int c=0;c<16;c++){ float d=v[c]-mu; var += d*d; }
    var *= (1.f/16.f);
    float inv = rsqrtf(var + 1e-5f);
    #pragma unroll
    for (int c=0;c<16;c++){
        float y = g[c]*(v[c]-mu)*inv + b[c];
        o[c] = (y>0.f) ? y : 0.01f*y;
    }
}

// ---------------- fuse + pooling ----------------
__global__ __launch_bounds__(256) void fuse_pool_kernel(
    const float* __restrict__ xt,
    const float* __restrict__ num_dt, const float* __restrict__ den_dt,
    const float* __restrict__ num_tt, const float* __restrict__ den_tt,
    const void* __restrict__ dt_res, const void* __restrict__ dt_bias,
    const void* __restrict__ tt_res, const void* __restrict__ tt_bias,
    const void* __restrict__ ln1g, const void* __restrict__ ln1b,
    const void* __restrict__ ln2g, const void* __restrict__ ln2b,
    const int* __restrict__ b_tasks, const int* __restrict__ ptrg,
    float* __restrict__ pool_sums, float* __restrict__ pool_cnt,
    void* __restrict__ out, const int* __restrict__ flag)
{
    int isbf = *flag;
    __shared__ float sdt[256], stt[256], sdb[16], stb[16], s1g[16], s1b[16], s2g[16], s2b[16];
    __shared__ int sptr[16];
    __shared__ int s_nonuni;
    __shared__ float red[256*48];
    int t = threadIdx.x;
    sdt[t] = ldf(dt_res, t, isbf);
    stt[t] = ldf(tt_res, t, isbf);
    if (t < 16){
        sdb[t]=ldf(dt_bias,t,isbf); stb[t]=ldf(tt_bias,t,isbf);
        s1g[t]=ldf(ln1g,t,isbf); s1b[t]=ldf(ln1b,t,isbf);
        s2g[t]=ldf(ln2g,t,isbf); s2b[t]=ldf(ln2b,t,isbf);
        sptr[t]=ptrg[t];
    }
    if (t==0) s_nonuni = 0;
    __syncthreads();
    long i = blockIdx.x*256 + t;
    const float4* xp = (const float4*)(xt + i*16);
    float4 x0=xp[0], x1=xp[1], x2=xp[2], x3=xp[3];
    float xv[16] = {x0.x,x0.y,x0.z,x0.w, x1.x,x1.y,x1.z,x1.w,
                    x2.x,x2.y,x2.z,x2.w, x3.x,x3.y,x3.z,x3.w};
    float dupd[16], tupd[16];
    {
        float id0 = 1.f/fmaxf(den_dt[i*2],   1e-16f);
        float id1 = 1.f/fmaxf(den_dt[i*2+1], 1e-16f);
        const float* nd = num_dt + i*32;
        float v[16];
        #pragma unroll
        for (int c=0;c<16;c++){
            float r = sdb[c];
            #pragma unroll
            for (int k=0;k<16;k++) r += xv[k]*sdt[k*16+c];
            v[c] = fin(0.5f*(nd[c]*id0 + nd[16+c]*id1) + r);
        }
        ln_act16(v, s1g, s1b, dupd);
    }
    {
        float id0 = 1.f/fmaxf(den_tt[i*2],   1e-16f);
        float id1 = 1.f/fmaxf(den_tt[i*2+1], 1e-16f);
        const float* nd = num_tt + i*32;
        float v[16];
        #pragma unroll
        for (int c=0;c<16;c++){
            float r = stb[c];
            #pragma unroll
            for (int k=0;k<16;k++) r += xv[k]*stt[k*16+c];
            v[c] = fin(0.5f*(nd[c]*id0 + nd[16+c]*id1) + r);
        }
        ln_act16(v, s2g, s2b, tupd);
    }
    #pragma unroll
    for (int j=0;j<16;j++){
        red[t*48+j]    = fin(xv[j]);
        red[t*48+16+j] = fin(tupd[j]);
        red[t*48+32+j] = fin(dupd[j]);
    }
    #pragma unroll
    for (int g=0; g<16; g++){
        if (i == sptr[g]){
            for (int j=0;j<16;j++){
                stf(out, g*96+j,    fin(xv[j]),   isbf);
                stf(out, g*96+16+j, fin(tupd[j]), isbf);
                stf(out, g*96+32+j, fin(dupd[j]), isbf);
            }
        }
    }
    int gi = b_tasks[i];
    int g0 = b_tasks[blockIdx.x*256];
    if (gi != g0) s_nonuni = 1;
    __syncthreads();
    if (s_nonuni){
        for (int j=0;j<48;j++) atomicAdd(&pool_sums[gi*48+j], red[t*48+j]);
        atomicAdd(&pool_cnt[gi], 1.f);
    } else {
        for (int stride=128; stride>0; stride>>=1){
            for (int idx=t; idx < stride*48; idx += 256){
                int r = idx/48, c = idx - r*48;
                red[r*48+c] += red[(r+stride)*48+c];
            }
            __syncthreads();
        }
        if (t < 48) atomicAdd(&pool_sums[g0*48+t], red[t]);
        if (t == 0) atomicAdd(&pool_cnt[g0], 256.f);
    }
}

__global__ void finish_kernel(const float* __restrict__ sums, const float* __restrict__ cnt,
                              void* __restrict__ out, const int* __restrict__ flag)
{
    int t = threadIdx.x;
    if (t >= 768) return;
    int g = t/48, c = t - g*48;
    stf(out, g*96+48+c, fin(sums[g*48+c]/fmaxf(cnt[g],1.f)), *flag);
}

extern "C" void kernel_launch(void* const* d_in, const int* in_sizes, int n_in,
                              void* d_out, int out_size, void* d_ws, size_t ws_size,
                              hipStream_t stream)
{
    const void* x_tasks  = d_in[0];
    const void* x_data   = d_in[1];
    const void* stem_t_W = d_in[2];
    const void* stem_t_b = d_in[3];
    const void* stem_d_W = d_in[4];
    const void* stem_d_b = d_in[5];
    const void* ln_t_g   = d_in[6];
    const void* ln_t_b   = d_in[7];
    const void* ln_d_g   = d_in[8];
    const void* ln_d_b   = d_in[9];
    const void* dt_Wl    = d_in[10];
    const void* dt_Wr    = d_in[11];
    const void* dt_att   = d_in[12];
    const void* dt_res   = d_in[13];
    const void* dt_bias  = d_in[14];
    const void* tt_Wl    = d_in[15];
    const void* tt_Wr    = d_in[16];
    const void* tt_att   = d_in[17];
    const void* tt_res   = d_in[18];
    const void* tt_bias  = d_in[19];
    const void* ln1_g    = d_in[20];
    const void* ln1_b    = d_in[21];
    const void* ln2_g    = d_in[22];
    const void* ln2_b    = d_in[23];
    const int*  ei_dt    = (const int*)d_in[24];
    const int*  mask_dt  = (const int*)d_in[25];
    const int*  ei_tt    = (const int*)d_in[26];
    const int*  b_tasks  = (const int*)d_in[27];
    const int*  ptrg     = (const int*)d_in[28];

    char* w = (char*)d_ws;
    const size_t MB = 1ull<<20;
    float* xt        = (float*)(w);            // 16 MB  [NT,16]
    float* xl        = (float*)(w + 16*MB);    // 32 MB  [N,32]
    float* xr        = (float*)(w + 48*MB);    // 32 MB  [NT,32]
    float* den_dt    = (float*)(w + 80*MB);    // 2 MB   [NT,2]
    float* den_tt    = (float*)(w + 82*MB);    // 2 MB
    float* num_dt    = (float*)(w + 84*MB);    // 32 MB  [NT,32]
    float* num_tt    = (float*)(w + 116*MB);   // 32 MB
    float* pool_sums = (float*)(w + 148*MB);   // 768 floats
    float* pool_cnt  = (float*)(w + 148*MB + 4096);
    int*   flag      = (int*)  (w + 149*MB);

    detect_kernel<<<1, 256, 0, stream>>>((const unsigned*)x_tasks, flag);

    // zero accumulators (80MB .. 148MB+8KB); flag at 149MB untouched
    hipMemsetAsync(w + 80*MB, 0, 68*MB + 8192, stream);

    stem_kernel<12><<<NT/256, 256, 0, stream>>>(x_tasks, stem_t_W, stem_t_b, ln_t_g, ln_t_b, xt, flag);
    stem_data_transform_kernel<<<ND/256, 256, 0, stream>>>(x_data, stem_d_W, stem_d_b,
                                                           ln_d_g, ln_d_b, dt_Wl, xl, flag);
    // d2t GAT
    transform_kernel<<<NT/256, 256, 0, stream>>>(xt, dt_Wr, xr, flag);
    edge_gat_kernel<<<EDT/256, 256, 0, stream>>>(ei_dt, mask_dt, xl, xr, dt_att, den_dt, num_dt, EDT, flag);

    // t2t GAT (reuse xl/xr)
    transform_kernel<<<NT/256, 256, 0, stream>>>(xt, tt_Wl, xl, flag);
    transform_kernel<<<NT/256, 256, 0, stream>>>(xt, tt_Wr, xr, flag);
    edge_gat_kernel<<<ETT/256, 256, 0, stream>>>(ei_tt, nullptr, xl, xr, tt_att, den_tt, num_tt, ETT, flag);

    fuse_pool_kernel<<<NT/256, 256, 0, stream>>>(xt, num_dt, den_dt, num_tt, den_tt,
        dt_res, dt_bias, tt_res, tt_bias, ln1_g, ln1_b, ln2_g, ln2_b,
        b_tasks, ptrg, pool_sums, pool_cnt, d_out, flag);
    finish_kernel<<<1, 768, 0, stream>>>(pool_sums, pool_cnt, d_out, flag);
}

// Round 4
// 837.746 us; speedup vs baseline: 4.7025x; 4.7025x over previous
//
#include <hip/hip_runtime.h>
#include <hip/hip_bf16.h>

typedef __hip_bfloat16 bf16;

#define NT 262144
#define ND 262144
#define EDT 2097152
#define ETT 1048576

// ---- dual-dtype load/store: isbf==1 -> bf16, else fp32 ----
__device__ __forceinline__ float ldf(const void* p, long i, int isbf){
    if (isbf) return __bfloat162float(((const bf16*)p)[i]);
    return ((const float*)p)[i];
}
__device__ __forceinline__ void stf(void* p, int i, float v, int isbf){
    if (isbf) ((bf16*)p)[i] = __float2bfloat16(v);
    else      ((float*)p)[i] = v;
}
__device__ __forceinline__ float fin(float x){
    return (x==x && x>-3e38f && x<3e38f) ? x : 0.f;
}

// ---- input dtype detection (see R2 notes): low-16-bit exponent census ----
__global__ void detect_kernel(const unsigned* __restrict__ raw, int* __restrict__ flag){
    __shared__ int cnt;
    if (threadIdx.x==0) cnt = 0;
    __syncthreads();
    int c = 0;
    for (int i = threadIdx.x; i < 2048; i += 256){
        unsigned w = raw[i];
        unsigned e = (w >> 7) & 0xFFu;
        if (e >= 116u && e <= 134u) c++;
    }
    atomicAdd(&cnt, c);
    __syncthreads();
    if (threadIdx.x==0) *flag = (cnt > 1024) ? 1 : 0;
}

// ---------------- stems ----------------
template<int F>
__global__ __launch_bounds__(256) void stem_kernel(
    const void* __restrict__ x, const void* __restrict__ W, const void* __restrict__ bias,
    const void* __restrict__ lng, const void* __restrict__ lnb, float* __restrict__ out,
    const int* __restrict__ flag)
{
    int isbf = *flag;
    __shared__ float sW[F*16], sb[16], sg[16], sbt[16];
    int t = threadIdx.x;
    if (t < F*16) sW[t] = ldf(W, t, isbf);
    if (t < 16){ sb[t]=ldf(bias,t,isbf); sg[t]=ldf(lng,t,isbf); sbt[t]=ldf(lnb,t,isbf); }
    __syncthreads();
    long i = blockIdx.x*256 + t;
    float f[F];
    #pragma unroll
    for (int k=0;k<F;k++) f[k] = ldf(x, i*F+k, isbf);
    float h[16];
    #pragma unroll
    for (int c=0;c<16;c++){
        float a = sb[c];
        #pragma unroll
        for (int k=0;k<F;k++) a += f[k]*sW[k*16+c];
        h[c]=a;
    }
    float mu=0.f;
    #pragma unroll
    for (int c=0;c<16;c++) mu += h[c];
    mu *= (1.f/16.f);
    float var=0.f;
    #pragma unroll
    for (int c=0;c<16;c++){ float d=h[c]-mu; var += d*d; }
    var *= (1.f/16.f);
    float inv = rsqrtf(var + 1e-5f);
    #pragma unroll
    for (int c=0;c<16;c++){
        float y = sg[c]*(h[c]-mu)*inv + sbt[c];
        out[i*16+c] = fin((y>0.f) ? y : 0.01f*y);
    }
}

// data stem fused with @Wl -> xl[ND,32]
__global__ __launch_bounds__(256) void stem_data_transform_kernel(
    const void* __restrict__ x, const void* __restrict__ W, const void* __restrict__ bias,
    const void* __restrict__ lng, const void* __restrict__ lnb,
    const void* __restrict__ Wl, float* __restrict__ xl,
    const int* __restrict__ flag)
{
    int isbf = *flag;
    __shared__ float sW[80], sb[16], sg[16], sbt[16], sWl[512];
    int t = threadIdx.x;
    if (t < 80) sW[t] = ldf(W, t, isbf);
    if (t < 16){ sb[t]=ldf(bias,t,isbf); sg[t]=ldf(lng,t,isbf); sbt[t]=ldf(lnb,t,isbf); }
    sWl[t]     = ldf(Wl, t,     isbf);
    sWl[t+256] = ldf(Wl, t+256, isbf);
    __syncthreads();
    long i = blockIdx.x*256 + t;
    float f[5];
    #pragma unroll
    for (int k=0;k<5;k++) f[k] = ldf(x, i*5+k, isbf);
    float h[16];
    #pragma unroll
    for (int c=0;c<16;c++){
        float a = sb[c];
        #pragma unroll
        for (int k=0;k<5;k++) a += f[k]*sW[k*16+c];
        h[c]=a;
    }
    float mu=0.f;
    #pragma unroll
    for (int c=0;c<16;c++) mu += h[c];
    mu *= (1.f/16.f);
    float var=0.f;
    #pragma unroll
    for (int c=0;c<16;c++){ float d=h[c]-mu; var += d*d; }
    var *= (1.f/16.f);
    float inv = rsqrtf(var + 1e-5f);
    float v[16];
    #pragma unroll
    for (int c=0;c<16;c++){
        float y = sg[c]*(h[c]-mu)*inv + sbt[c];
        v[c] = (y>0.f) ? y : 0.01f*y;
    }
    float o[32];
    #pragma unroll
    for (int c=0;c<32;c++) o[c]=0.f;
    #pragma unroll
    for (int k=0;k<16;k++){
        float xv=v[k];
        #pragma unroll
        for (int c=0;c<32;c++) o[c] += xv*sWl[k*32+c];
    }
    float4* op = (float4*)(xl + i*32);
    #pragma unroll
    for (int q=0;q<8;q++)
        op[q] = make_float4(fin(o[q*4]),fin(o[q*4+1]),fin(o[q*4+2]),fin(o[q*4+3]));
}

// 16 -> 32 transform (xl/xr)
__global__ __launch_bounds__(256) void transform_kernel(
    const float* __restrict__ x, const void* __restrict__ W, float* __restrict__ out,
    const int* __restrict__ flag)
{
    int isbf = *flag;
    __shared__ float sW[512];
    int t = threadIdx.x;
    sW[t]     = ldf(W, t,     isbf);
    sW[t+256] = ldf(W, t+256, isbf);
    __syncthreads();
    long i = blockIdx.x*256 + t;
    const float4* xp = (const float4*)(x + i*16);
    float4 x0=xp[0], x1=xp[1], x2=xp[2], x3=xp[3];
    float xi[16] = {x0.x,x0.y,x0.z,x0.w, x1.x,x1.y,x1.z,x1.w,
                    x2.x,x2.y,x2.z,x2.w, x3.x,x3.y,x3.z,x3.w};
    float o[32];
    #pragma unroll
    for (int c=0;c<32;c++) o[c]=0.f;
    #pragma unroll
    for (int k=0;k<16;k++){
        float xv=xi[k];
        #pragma unroll
        for (int c=0;c<32;c++) o[c] += xv*sW[k*32+c];
    }
    float4* op = (float4*)(out + i*32);
    #pragma unroll
    for (int q=0;q<8;q++)
        op[q] = make_float4(fin(o[q*4]),fin(o[q*4+1]),fin(o[q*4+2]),fin(o[q*4+3]));
}

// ---------------- CSR build: histogram -> scan -> scatter ----------------
__global__ __launch_bounds__(256) void hist_kernel(
    const int* __restrict__ ei, const int* __restrict__ mask,
    int* __restrict__ cnt, int E)
{
    int e = blockIdx.x*256 + threadIdx.x;
    if (e >= E) return;
    if (mask && mask[e]==0) return;
    atomicAdd(&cnt[ei[E+e]], 1);
}

// single-workgroup scan over NT counts; writes exclusive offsets into offs[0..NT]
// and also into cnt (reused as scatter cursors). 1024 threads x 256 elems.
__global__ __launch_bounds__(1024) void scan_kernel(
    int* __restrict__ cnt, int* __restrict__ offs)
{
    __shared__ int part[1024];
    int t = threadIdx.x;
    int base = t*256;
    int s = 0;
    for (int i=0;i<256;i++) s += cnt[base+i];
    part[t] = s;
    __syncthreads();
    // Hillis-Steele inclusive scan over 1024 partials
    for (int off=1; off<1024; off<<=1){
        int v = part[t];
        int add = (t>=off) ? part[t-off] : 0;
        __syncthreads();
        part[t] = v + add;
        __syncthreads();
    }
    int running = part[t] - s;   // exclusive prefix at chunk start
    for (int i=0;i<256;i++){
        int c = cnt[base+i];
        offs[base+i] = running;
        cnt[base+i]  = running;  // scatter cursor
        running += c;
    }
    if (t==1023) offs[NT] = part[1023];
}

__global__ __launch_bounds__(256) void scatter_kernel(
    const int* __restrict__ ei, const int* __restrict__ mask,
    int* __restrict__ cursor, int* __restrict__ esrc, int E)
{
    int e = blockIdx.x*256 + threadIdx.x;
    if (e >= E) return;
    if (mask && mask[e]==0) return;
    int s = ei[e], d = ei[E+e];
    int pos = atomicAdd(&cursor[d], 1);
    esrc[pos] = s;
}

// ---------------- dst-centric GAT aggregation: no float atomics ----------------
// One thread per dst node: walk its CSR edge list, score -> exp -> accumulate in
// registers, normalize + head-mean locally, write 16-ch result.
__global__ __launch_bounds__(256) void aggregate_kernel(
    const int* __restrict__ offs, const int* __restrict__ esrc,
    const float* __restrict__ xl, const float* __restrict__ xr,
    const void* __restrict__ att, float* __restrict__ agg,
    const int* __restrict__ flag)
{
    __shared__ float satt[32];
    if (threadIdx.x < 32) satt[threadIdx.x] = ldf(att, threadIdx.x, *flag);
    __syncthreads();
    long d = blockIdx.x*256 + threadIdx.x;
    const float4* r4 = (const float4*)(xr + d*32);
    float xrv[32];
    #pragma unroll
    for (int q=0;q<8;q++){
        float4 r = r4[q];
        xrv[q*4]=r.x; xrv[q*4+1]=r.y; xrv[q*4+2]=r.z; xrv[q*4+3]=r.w;
    }
    float acc[32];
    #pragma unroll
    for (int c=0;c<32;c++) acc[c]=0.f;
    float den0=0.f, den1=0.f;
    int e0 = offs[d], e1 = offs[d+1];
    for (int e=e0; e<e1; e++){
        long s = esrc[e];
        const float4* a4 = (const float4*)(xl + s*32);
        float xs[32];
        float sc0=0.f, sc1=0.f;
        #pragma unroll
        for (int q=0;q<8;q++){
            float4 a = a4[q];
            xs[q*4]=a.x; xs[q*4+1]=a.y; xs[q*4+2]=a.z; xs[q*4+3]=a.w;
            float m0=a.x+xrv[q*4], m1=a.y+xrv[q*4+1], m2=a.z+xrv[q*4+2], m3=a.w+xrv[q*4+3];
            m0 = m0>0.f?m0:0.2f*m0; m1 = m1>0.f?m1:0.2f*m1;
            m2 = m2>0.f?m2:0.2f*m2; m3 = m3>0.f?m3:0.2f*m3;
            float p = m0*satt[q*4] + m1*satt[q*4+1] + m2*satt[q*4+2] + m3*satt[q*4+3];
            if (q < 4) sc0 += p; else sc1 += p;
        }
        float a0 = expf(fminf(fin(sc0), 60.f));
        float a1 = expf(fminf(fin(sc1), 60.f));
        den0 += a0; den1 += a1;
        #pragma unroll
        for (int c=0;c<16;c++){
            acc[c]    += a0*xs[c];
            acc[16+c] += a1*xs[16+c];
        }
    }
    float id0 = 1.f/fmaxf(den0, 1e-16f);
    float id1 = 1.f/fmaxf(den1, 1e-16f);
    float4* op = (float4*)(agg + d*16);
    #pragma unroll
    for (int q=0;q<4;q++){
        op[q] = make_float4(
            fin(0.5f*(acc[q*4  ]*id0 + acc[16+q*4  ]*id1)),
            fin(0.5f*(acc[q*4+1]*id0 + acc[16+q*4+1]*id1)),
            fin(0.5f*(acc[q*4+2]*id0 + acc[16+q*4+2]*id1)),
            fin(0.5f*(acc[q*4+3]*id0 + acc[16+q*4+3]*id1)));
    }
}

__device__ __forceinline__ void ln_act16(const float* v, const float* g, const float* b, float* o){
    float mu=0.f;
    #pragma unroll
    for (int c=0;c<16;c++) mu += v[c];
    mu *= (1.f/16.f);
    float var=0.f;
    #pragma unroll
    for (int c=0;c<16;c++){ float d=v[c]-mu; var += d*d; }
    var *= (1.f/16.f);
    float inv = rsqrtf(var + 1e-5f);
    #pragma unroll
    for (int c=0;c<16;c++){
        float y = g[c]*(v[c]-mu)*inv + b[c];
        o[c] = (y>0.f) ? y : 0.01f*y;
    }
}

// ---------------- fuse + pooling ----------------
__global__ __launch_bounds__(256) void fuse_pool_kernel(
    const float* __restrict__ xt,
    const float* __restrict__ agg_dt, const float* __restrict__ agg_tt,
    const void* __restrict__ dt_res, const void* __restrict__ dt_bias,
    const void* __restrict__ tt_res, const void* __restrict__ tt_bias,
    const void* __restrict__ ln1g, const void* __restrict__ ln1b,
    const void* __restrict__ ln2g, const void* __restrict__ ln2b,
    const int* __restrict__ b_tasks, const int* __restrict__ ptrg,
    float* __restrict__ pool_sums, float* __restrict__ pool_cnt,
    void* __restrict__ out, const int* __restrict__ flag)
{
    int isbf = *flag;
    __shared__ float sdt[256], stt[256], sdb[16], stb[16], s1g[16], s1b[16], s2g[16], s2b[16];
    __shared__ int sptr[16];
    __shared__ int s_nonuni;
    __shared__ float red[256*48];
    int t = threadIdx.x;
    sdt[t] = ldf(dt_res, t, isbf);
    stt[t] = ldf(tt_res, t, isbf);
    if (t < 16){
        sdb[t]=ldf(dt_bias,t,isbf); stb[t]=ldf(tt_bias,t,isbf);
        s1g[t]=ldf(ln1g,t,isbf); s1b[t]=ldf(ln1b,t,isbf);
        s2g[t]=ldf(ln2g,t,isbf); s2b[t]=ldf(ln2b,t,isbf);
        sptr[t]=ptrg[t];
    }
    if (t==0) s_nonuni = 0;
    __syncthreads();
    long i = blockIdx.x*256 + t;
    const float4* xp = (const float4*)(xt + i*16);
    float4 x0=xp[0], x1=xp[1], x2=xp[2], x3=xp[3];
    float xv[16] = {x0.x,x0.y,x0.z,x0.w, x1.x,x1.y,x1.z,x1.w,
                    x2.x,x2.y,x2.z,x2.w, x3.x,x3.y,x3.z,x3.w};
    float dupd[16], tupd[16];
    {
        const float* ag = agg_dt + i*16;
        float v[16];
        #pragma unroll
        for (int c=0;c<16;c++){
            float r = sdb[c];
            #pragma unroll
            for (int k=0;k<16;k++) r += xv[k]*sdt[k*16+c];
            v[c] = fin(ag[c] + r);
        }
        ln_act16(v, s1g, s1b, dupd);
    }
    {
        const float* ag = agg_tt + i*16;
        float v[16];
        #pragma unroll
        for (int c=0;c<16;c++){
            float r = stb[c];
            #pragma unroll
            for (int k=0;k<16;k++) r += xv[k]*stt[k*16+c];
            v[c] = fin(ag[c] + r);
        }
        ln_act16(v, s2g, s2b, tupd);
    }
    #pragma unroll
    for (int j=0;j<16;j++){
        red[t*48+j]    = fin(xv[j]);
        red[t*48+16+j] = fin(tupd[j]);
        red[t*48+32+j] = fin(dupd[j]);
    }
    #pragma unroll
    for (int g=0; g<16; g++){
        if (i == sptr[g]){
            for (int j=0;j<16;j++){
                stf(out, g*96+j,    fin(xv[j]),   isbf);
                stf(out, g*96+16+j, fin(tupd[j]), isbf);
                stf(out, g*96+32+j, fin(dupd[j]), isbf);
            }
        }
    }
    int gi = b_tasks[i];
    int g0 = b_tasks[blockIdx.x*256];
    if (gi != g0) s_nonuni = 1;
    __syncthreads();
    if (s_nonuni){
        for (int j=0;j<48;j++) atomicAdd(&pool_sums[gi*48+j], red[t*48+j]);
        atomicAdd(&pool_cnt[gi], 1.f);
    } else {
        for (int stride=128; stride>0; stride>>=1){
            for (int idx=t; idx < stride*48; idx += 256){
                int r = idx/48, c = idx - r*48;
                red[r*48+c] += red[(r+stride)*48+c];
            }
            __syncthreads();
        }
        if (t < 48) atomicAdd(&pool_sums[g0*48+t], red[t]);
        if (t == 0) atomicAdd(&pool_cnt[g0], 256.f);
    }
}

__global__ void finish_kernel(const float* __restrict__ sums, const float* __restrict__ cnt,
                              void* __restrict__ out, const int* __restrict__ flag)
{
    int t = threadIdx.x;
    if (t >= 768) return;
    int g = t/48, c = t - g*48;
    stf(out, g*96+48+c, fin(sums[g*48+c]/fmaxf(cnt[g],1.f)), *flag);
}

extern "C" void kernel_launch(void* const* d_in, const int* in_sizes, int n_in,
                              void* d_out, int out_size, void* d_ws, size_t ws_size,
                              hipStream_t stream)
{
    const void* x_tasks  = d_in[0];
    const void* x_data   = d_in[1];
    const void* stem_t_W = d_in[2];
    const void* stem_t_b = d_in[3];
    const void* stem_d_W = d_in[4];
    const void* stem_d_b = d_in[5];
    const void* ln_t_g   = d_in[6];
    const void* ln_t_b   = d_in[7];
    const void* ln_d_g   = d_in[8];
    const void* ln_d_b   = d_in[9];
    const void* dt_Wl    = d_in[10];
    const void* dt_Wr    = d_in[11];
    const void* dt_att   = d_in[12];
    const void* dt_res   = d_in[13];
    const void* dt_bias  = d_in[14];
    const void* tt_Wl    = d_in[15];
    const void* tt_Wr    = d_in[16];
    const void* tt_att   = d_in[17];
    const void* tt_res   = d_in[18];
    const void* tt_bias  = d_in[19];
    const void* ln1_g    = d_in[20];
    const void* ln1_b    = d_in[21];
    const void* ln2_g    = d_in[22];
    const void* ln2_b    = d_in[23];
    const int*  ei_dt    = (const int*)d_in[24];
    const int*  mask_dt  = (const int*)d_in[25];
    const int*  ei_tt    = (const int*)d_in[26];
    const int*  b_tasks  = (const int*)d_in[27];
    const int*  ptrg     = (const int*)d_in[28];

    char* w = (char*)d_ws;
    const size_t MB = 1ull<<20;
    float* xt        = (float*)(w);             // 16 MB  [NT,16]
    float* xl        = (float*)(w + 16*MB);     // 32 MB  [N,32]
    float* xr        = (float*)(w + 48*MB);     // 32 MB  [NT,32]
    float* agg_dt    = (float*)(w + 80*MB);     // 16 MB  [NT,16]
    float* agg_tt    = (float*)(w + 96*MB);     // 16 MB
    int*   offs      = (int*)  (w + 112*MB);    // (NT+1) ints
    int*   cursor    = (int*)  (w + 114*MB);    // NT ints (counts, then cursors)
    int*   esrc      = (int*)  (w + 116*MB);    // up to EDT ints (8 MB)
    float* pool_sums = (float*)(w + 124*MB);    // 768 floats
    float* pool_cnt  = (float*)(w + 124*MB + 4096);
    int*   flag      = (int*)  (w + 124*MB + 8192);

    detect_kernel<<<1, 256, 0, stream>>>((const unsigned*)x_tasks, flag);

    // pool accumulators (sums + cnt); flag is past this region and set above
    hipMemsetAsync(w + 124*MB, 0, 8192, stream);

    // stems
    stem_kernel<12><<<NT/256, 256, 0, stream>>>(x_tasks, stem_t_W, stem_t_b, ln_t_g, ln_t_b, xt, flag);
    stem_data_transform_kernel<<<ND/256, 256, 0, stream>>>(x_data, stem_d_W, stem_d_b,
                                                           ln_d_g, ln_d_b, dt_Wl, xl, flag);
    // ---- d2t GAT ----
    transform_kernel<<<NT/256, 256, 0, stream>>>(xt, dt_Wr, xr, flag);
    hipMemsetAsync(cursor, 0, NT*sizeof(int), stream);
    hist_kernel<<<EDT/256, 256, 0, stream>>>(ei_dt, mask_dt, cursor, EDT);
    scan_kernel<<<1, 1024, 0, stream>>>(cursor, offs);
    scatter_kernel<<<EDT/256, 256, 0, stream>>>(ei_dt, mask_dt, cursor, esrc, EDT);
    aggregate_kernel<<<NT/256, 256, 0, stream>>>(offs, esrc, xl, xr, dt_att, agg_dt, flag);

    // ---- t2t GAT (reuse xl/xr/CSR buffers) ----
    transform_kernel<<<NT/256, 256, 0, stream>>>(xt, tt_Wl, xl, flag);
    transform_kernel<<<NT/256, 256, 0, stream>>>(xt, tt_Wr, xr, flag);
    hipMemsetAsync(cursor, 0, NT*sizeof(int), stream);
    hist_kernel<<<ETT/256, 256, 0, stream>>>(ei_tt, nullptr, cursor, ETT);
    scan_kernel<<<1, 1024, 0, stream>>>(cursor, offs);
    scatter_kernel<<<ETT/256, 256, 0, stream>>>(ei_tt, nullptr, cursor, esrc, ETT);
    aggregate_kernel<<<NT/256, 256, 0, stream>>>(offs, esrc, xl, xr, tt_att, agg_tt, flag);

    // fuse + pool + output
    fuse_pool_kernel<<<NT/256, 256, 0, stream>>>(xt, agg_dt, agg_tt,
        dt_res, dt_bias, tt_res, tt_bias, ln1_g, ln1_b, ln2_g, ln2_b,
        b_tasks, ptrg, pool_sums, pool_cnt, d_out, flag);
    finish_kernel<<<1, 768, 0, stream>>>(pool_sums, pool_cnt, d_out, flag);
}

// Round 5
// 590.999 us; speedup vs baseline: 6.6658x; 1.4175x over previous
//
#include <hip/hip_runtime.h>
#include <hip/hip_bf16.h>

typedef __hip_bfloat16 bf16;

#define NT 262144
#define ND 262144
#define EDT 2097152
#define ETT 1048576

// ---- dual-dtype load/store: isbf==1 -> bf16, else fp32 ----
__device__ __forceinline__ float ldf(const void* p, long i, int isbf){
    if (isbf) return __bfloat162float(((const bf16*)p)[i]);
    return ((const float*)p)[i];
}
__device__ __forceinline__ void stf(void* p, int i, float v, int isbf){
    if (isbf) ((bf16*)p)[i] = __float2bfloat16(v);
    else      ((float*)p)[i] = v;
}
__device__ __forceinline__ float fin(float x){
    return (x==x && x>-3e38f && x<3e38f) ? x : 0.f;
}

// ---- input dtype detection: low-16-bit exponent census (see R2 notes) ----
__global__ void detect_kernel(const unsigned* __restrict__ raw, int* __restrict__ flag){
    __shared__ int cnt;
    if (threadIdx.x==0) cnt = 0;
    __syncthreads();
    int c = 0;
    for (int i = threadIdx.x; i < 2048; i += 256){
        unsigned w = raw[i];
        unsigned e = (w >> 7) & 0xFFu;
        if (e >= 116u && e <= 134u) c++;
    }
    atomicAdd(&cnt, c);
    __syncthreads();
    if (threadIdx.x==0) *flag = (cnt > 1024) ? 1 : 0;
}

// ---------------- task stem fused with @dt_Wr -> xt[NT,16] and xr_dt[NT,32] ----------------
__global__ __launch_bounds__(256) void stem_task_kernel(
    const void* __restrict__ x, const void* __restrict__ W, const void* __restrict__ bias,
    const void* __restrict__ lng, const void* __restrict__ lnb,
    const void* __restrict__ Wr, float* __restrict__ xt, float* __restrict__ xr,
    const int* __restrict__ flag)
{
    int isbf = *flag;
    __shared__ float sW[192], sb[16], sg[16], sbt[16], sWr[512];
    int t = threadIdx.x;
    if (t < 192) sW[t] = ldf(W, t, isbf);
    if (t < 16){ sb[t]=ldf(bias,t,isbf); sg[t]=ldf(lng,t,isbf); sbt[t]=ldf(lnb,t,isbf); }
    sWr[t]     = ldf(Wr, t,     isbf);
    sWr[t+256] = ldf(Wr, t+256, isbf);
    __syncthreads();
    long i = blockIdx.x*256 + t;
    float f[12];
    #pragma unroll
    for (int k=0;k<12;k++) f[k] = ldf(x, i*12+k, isbf);
    float h[16];
    #pragma unroll
    for (int c=0;c<16;c++){
        float a = sb[c];
        #pragma unroll
        for (int k=0;k<12;k++) a += f[k]*sW[k*16+c];
        h[c]=a;
    }
    float mu=0.f;
    #pragma unroll
    for (int c=0;c<16;c++) mu += h[c];
    mu *= (1.f/16.f);
    float var=0.f;
    #pragma unroll
    for (int c=0;c<16;c++){ float d=h[c]-mu; var += d*d; }
    var *= (1.f/16.f);
    float inv = rsqrtf(var + 1e-5f);
    float v[16];
    #pragma unroll
    for (int c=0;c<16;c++){
        float y = sg[c]*(h[c]-mu)*inv + sbt[c];
        v[c] = fin((y>0.f) ? y : 0.01f*y);
    }
    float4* xp = (float4*)(xt + i*16);
    #pragma unroll
    for (int q=0;q<4;q++) xp[q] = make_float4(v[q*4],v[q*4+1],v[q*4+2],v[q*4+3]);
    float o[32];
    #pragma unroll
    for (int c=0;c<32;c++) o[c]=0.f;
    #pragma unroll
    for (int k=0;k<16;k++){
        float xv=v[k];
        #pragma unroll
        for (int c=0;c<32;c++) o[c] += xv*sWr[k*32+c];
    }
    float4* op = (float4*)(xr + i*32);
    #pragma unroll
    for (int q=0;q<8;q++)
        op[q] = make_float4(fin(o[q*4]),fin(o[q*4+1]),fin(o[q*4+2]),fin(o[q*4+3]));
}

// data stem fused with @Wl -> xl[ND,32]
__global__ __launch_bounds__(256) void stem_data_transform_kernel(
    const void* __restrict__ x, const void* __restrict__ W, const void* __restrict__ bias,
    const void* __restrict__ lng, const void* __restrict__ lnb,
    const void* __restrict__ Wl, float* __restrict__ xl,
    const int* __restrict__ flag)
{
    int isbf = *flag;
    __shared__ float sW[80], sb[16], sg[16], sbt[16], sWl[512];
    int t = threadIdx.x;
    if (t < 80) sW[t] = ldf(W, t, isbf);
    if (t < 16){ sb[t]=ldf(bias,t,isbf); sg[t]=ldf(lng,t,isbf); sbt[t]=ldf(lnb,t,isbf); }
    sWl[t]     = ldf(Wl, t,     isbf);
    sWl[t+256] = ldf(Wl, t+256, isbf);
    __syncthreads();
    long i = blockIdx.x*256 + t;
    float f[5];
    #pragma unroll
    for (int k=0;k<5;k++) f[k] = ldf(x, i*5+k, isbf);
    float h[16];
    #pragma unroll
    for (int c=0;c<16;c++){
        float a = sb[c];
        #pragma unroll
        for (int k=0;k<5;k++) a += f[k]*sW[k*16+c];
        h[c]=a;
    }
    float mu=0.f;
    #pragma unroll
    for (int c=0;c<16;c++) mu += h[c];
    mu *= (1.f/16.f);
    float var=0.f;
    #pragma unroll
    for (int c=0;c<16;c++){ float d=h[c]-mu; var += d*d; }
    var *= (1.f/16.f);
    float inv = rsqrtf(var + 1e-5f);
    float v[16];
    #pragma unroll
    for (int c=0;c<16;c++){
        float y = sg[c]*(h[c]-mu)*inv + sbt[c];
        v[c] = (y>0.f) ? y : 0.01f*y;
    }
    float o[32];
    #pragma unroll
    for (int c=0;c<32;c++) o[c]=0.f;
    #pragma unroll
    for (int k=0;k<16;k++){
        float xv=v[k];
        #pragma unroll
        for (int c=0;c<32;c++) o[c] += xv*sWl[k*32+c];
    }
    float4* op = (float4*)(xl + i*32);
    #pragma unroll
    for (int q=0;q<8;q++)
        op[q] = make_float4(fin(o[q*4]),fin(o[q*4+1]),fin(o[q*4+2]),fin(o[q*4+3]));
}

// dual 16->32 transform for tt (one read of xt, both outputs)
__global__ __launch_bounds__(256) void transform2_kernel(
    const float* __restrict__ x, const void* __restrict__ Wl, const void* __restrict__ Wr,
    float* __restrict__ xl, float* __restrict__ xr, const int* __restrict__ flag)
{
    int isbf = *flag;
    __shared__ float sWl[512], sWr[512];
    int t = threadIdx.x;
    sWl[t]     = ldf(Wl, t,     isbf);
    sWl[t+256] = ldf(Wl, t+256, isbf);
    sWr[t]     = ldf(Wr, t,     isbf);
    sWr[t+256] = ldf(Wr, t+256, isbf);
    __syncthreads();
    long i = blockIdx.x*256 + t;
    const float4* xp = (const float4*)(x + i*16);
    float4 x0=xp[0], x1=xp[1], x2=xp[2], x3=xp[3];
    float xi[16] = {x0.x,x0.y,x0.z,x0.w, x1.x,x1.y,x1.z,x1.w,
                    x2.x,x2.y,x2.z,x2.w, x3.x,x3.y,x3.z,x3.w};
    float o[32];
    #pragma unroll
    for (int c=0;c<32;c++) o[c]=0.f;
    #pragma unroll
    for (int k=0;k<16;k++){
        float xv=xi[k];
        #pragma unroll
        for (int c=0;c<32;c++) o[c] += xv*sWl[k*32+c];
    }
    float4* ol = (float4*)(xl + i*32);
    #pragma unroll
    for (int q=0;q<8;q++)
        ol[q] = make_float4(fin(o[q*4]),fin(o[q*4+1]),fin(o[q*4+2]),fin(o[q*4+3]));
    #pragma unroll
    for (int c=0;c<32;c++) o[c]=0.f;
    #pragma unroll
    for (int k=0;k<16;k++){
        float xv=xi[k];
        #pragma unroll
        for (int c=0;c<32;c++) o[c] += xv*sWr[k*32+c];
    }
    float4* orr = (float4*)(xr + i*32);
    #pragma unroll
    for (int q=0;q<8;q++)
        orr[q] = make_float4(fin(o[q*4]),fin(o[q*4+1]),fin(o[q*4+2]),fin(o[q*4+3]));
}

// ---------------- CSR build: histogram -> hierarchical scan -> scatter ----------------
__global__ __launch_bounds__(256) void hist_kernel(
    const int* __restrict__ ei, const int* __restrict__ mask,
    int* __restrict__ cnt, int E)
{
    int e = blockIdx.x*256 + threadIdx.x;
    if (e >= E) return;
    if (mask && mask[e]==0) return;
    atomicAdd(&cnt[ei[E+e]], 1);
}

// stage 1: per-block (256-chunk) sums -> bsum[1024]
__global__ __launch_bounds__(256) void scan1_kernel(const int* __restrict__ cnt, int* __restrict__ bsum)
{
    __shared__ int red[256];
    int t = threadIdx.x;
    red[t] = cnt[blockIdx.x*256 + t];
    __syncthreads();
    for (int s=128; s>0; s>>=1){
        if (t < s) red[t] += red[t+s];
        __syncthreads();
    }
    if (t==0) bsum[blockIdx.x] = red[0];
}
// stage 2: exclusive scan of 1024 block sums (single block)
__global__ __launch_bounds__(1024) void scan2_kernel(int* __restrict__ bsum)
{
    __shared__ int part[1024];
    int t = threadIdx.x;
    int v = bsum[t];
    part[t] = v;
    __syncthreads();
    for (int off=1; off<1024; off<<=1){
        int x = part[t];
        int add = (t>=off) ? part[t-off] : 0;
        __syncthreads();
        part[t] = x + add;
        __syncthreads();
    }
    bsum[t] = part[t] - v;   // exclusive
}
// stage 3: local exclusive scan + block offset; writes offs[0..NT] and cursors
__global__ __launch_bounds__(256) void scan3_kernel(
    int* __restrict__ cnt, const int* __restrict__ bsum, int* __restrict__ offs)
{
    __shared__ int part[256];
    int t = threadIdx.x;
    int i = blockIdx.x*256 + t;
    int v = cnt[i];
    part[t] = v;
    __syncthreads();
    for (int off=1; off<256; off<<=1){
        int x = part[t];
        int add = (t>=off) ? part[t-off] : 0;
        __syncthreads();
        part[t] = x + add;
        __syncthreads();
    }
    int ex = part[t] - v + bsum[blockIdx.x];
    offs[i] = ex;
    cnt[i]  = ex;   // scatter cursor
    if (blockIdx.x == gridDim.x-1 && t == 255) offs[NT] = ex + v;
}

__global__ __launch_bounds__(256) void scatter_kernel(
    const int* __restrict__ ei, const int* __restrict__ mask,
    int* __restrict__ cursor, int* __restrict__ esrc, int E)
{
    int e = blockIdx.x*256 + threadIdx.x;
    if (e >= E) return;
    if (mask && mask[e]==0) return;
    int s = ei[e], d = ei[E+e];
    int pos = atomicAdd(&cursor[d], 1);
    esrc[pos] = s;
}

// ---------------- dst-centric GAT aggregation: no float atomics ----------------
__global__ __launch_bounds__(256) void aggregate_kernel(
    const int* __restrict__ offs, const int* __restrict__ esrc,
    const float* __restrict__ xl, const float* __restrict__ xr,
    const void* __restrict__ att, float* __restrict__ agg,
    const int* __restrict__ flag)
{
    __shared__ float satt[32];
    if (threadIdx.x < 32) satt[threadIdx.x] = ldf(att, threadIdx.x, *flag);
    __syncthreads();
    long d = blockIdx.x*256 + threadIdx.x;
    const float4* r4 = (const float4*)(xr + d*32);
    float xrv[32];
    #pragma unroll
    for (int q=0;q<8;q++){
        float4 r = r4[q];
        xrv[q*4]=r.x; xrv[q*4+1]=r.y; xrv[q*4+2]=r.z; xrv[q*4+3]=r.w;
    }
    float acc[32];
    #pragma unroll
    for (int c=0;c<32;c++) acc[c]=0.f;
    float den0=0.f, den1=0.f;
    int e0 = offs[d], e1 = offs[d+1];
    for (int e=e0; e<e1; e++){
        long s = esrc[e];
        const float4* a4 = (const float4*)(xl + s*32);
        float xs[32];
        float sc0=0.f, sc1=0.f;
        #pragma unroll
        for (int q=0;q<8;q++){
            float4 a = a4[q];
            xs[q*4]=a.x; xs[q*4+1]=a.y; xs[q*4+2]=a.z; xs[q*4+3]=a.w;
            float m0=a.x+xrv[q*4], m1=a.y+xrv[q*4+1], m2=a.z+xrv[q*4+2], m3=a.w+xrv[q*4+3];
            m0 = m0>0.f?m0:0.2f*m0; m1 = m1>0.f?m1:0.2f*m1;
            m2 = m2>0.f?m2:0.2f*m2; m3 = m3>0.f?m3:0.2f*m3;
            float p = m0*satt[q*4] + m1*satt[q*4+1] + m2*satt[q*4+2] + m3*satt[q*4+3];
            if (q < 4) sc0 += p; else sc1 += p;
        }
        float a0 = expf(fminf(fin(sc0), 60.f));
        float a1 = expf(fminf(fin(sc1), 60.f));
        den0 += a0; den1 += a1;
        #pragma unroll
        for (int c=0;c<16;c++){
            acc[c]    += a0*xs[c];
            acc[16+c] += a1*xs[16+c];
        }
    }
    float id0 = 1.f/fmaxf(den0, 1e-16f);
    float id1 = 1.f/fmaxf(den1, 1e-16f);
    float4* op = (float4*)(agg + d*16);
    #pragma unroll
    for (int q=0;q<4;q++){
        op[q] = make_float4(
            fin(0.5f*(acc[q*4  ]*id0 + acc[16+q*4  ]*id1)),
            fin(0.5f*(acc[q*4+1]*id0 + acc[16+q*4+1]*id1)),
            fin(0.5f*(acc[q*4+2]*id0 + acc[16+q*4+2]*id1)),
            fin(0.5f*(acc[q*4+3]*id0 + acc[16+q*4+3]*id1)));
    }
}

__device__ __forceinline__ void ln_act16(const float* v, const float* g, const float* b, float* o){
    float mu=0.f;
    #pragma unroll
    for (int c=0;c<16;c++) mu += v[c];
    mu *= (1.f/16.f);
    float var=0.f;
    #pragma unroll
    for (int c=0;c<16;c++){ float d=v[c]-mu; var += d*d; }
    var *= (1.f/16.f);
    float inv = rsqrtf(var + 1e-5f);
    #pragma unroll
    for (int c=0;c<16;c++){
        float y = g[c]*(v[c]-mu)*inv + b[c];
        o[c] = (y>0.f) ? y : 0.01f*y;
    }
}

// ---------------- fuse + pooling (wave-shuffle reduction, ~1KB LDS) ----------------
__global__ __launch_bounds__(256) void fuse_pool_kernel(
    const float* __restrict__ xt,
    const float* __restrict__ agg_dt, const float* __restrict__ agg_tt,
    const void* __restrict__ dt_res, const void* __restrict__ dt_bias,
    const void* __restrict__ tt_res, const void* __restrict__ tt_bias,
    const void* __restrict__ ln1g, const void* __restrict__ ln1b,
    const void* __restrict__ ln2g, const void* __restrict__ ln2b,
    const int* __restrict__ b_tasks, const int* __restrict__ ptrg,
    float* __restrict__ pool_sums, float* __restrict__ pool_cnt,
    void* __restrict__ out, const int* __restrict__ flag)
{
    int isbf = *flag;
    __shared__ float sdt[256], stt[256], sdb[16], stb[16], s1g[16], s1b[16], s2g[16], s2b[16];
    __shared__ float swave[4*48];
    __shared__ int sptr[16];
    __shared__ int s_nonuni;
    int t = threadIdx.x;
    sdt[t] = ldf(dt_res, t, isbf);
    stt[t] = ldf(tt_res, t, isbf);
    if (t < 16){
        sdb[t]=ldf(dt_bias,t,isbf); stb[t]=ldf(tt_bias,t,isbf);
        s1g[t]=ldf(ln1g,t,isbf); s1b[t]=ldf(ln1b,t,isbf);
        s2g[t]=ldf(ln2g,t,isbf); s2b[t]=ldf(ln2b,t,isbf);
        sptr[t]=ptrg[t];
    }
    if (t==0) s_nonuni = 0;
    __syncthreads();
    long i = blockIdx.x*256 + t;
    const float4* xp = (const float4*)(xt + i*16);
    float4 x0=xp[0], x1=xp[1], x2=xp[2], x3=xp[3];
    float vals[48];
    float* xv   = vals;
    float* tupd = vals+16;
    float* dupd = vals+32;
    xv[0]=x0.x; xv[1]=x0.y; xv[2]=x0.z; xv[3]=x0.w;
    xv[4]=x1.x; xv[5]=x1.y; xv[6]=x1.z; xv[7]=x1.w;
    xv[8]=x2.x; xv[9]=x2.y; xv[10]=x2.z; xv[11]=x2.w;
    xv[12]=x3.x; xv[13]=x3.y; xv[14]=x3.z; xv[15]=x3.w;
    {
        const float* ag = agg_dt + i*16;
        float v[16];
        #pragma unroll
        for (int c=0;c<16;c++){
            float r = sdb[c];
            #pragma unroll
            for (int k=0;k<16;k++) r += xv[k]*sdt[k*16+c];
            v[c] = fin(ag[c] + r);
        }
        ln_act16(v, s1g, s1b, dupd);
    }
    {
        const float* ag = agg_tt + i*16;
        float v[16];
        #pragma unroll
        for (int c=0;c<16;c++){
            float r = stb[c];
            #pragma unroll
            for (int k=0;k<16;k++) r += xv[k]*stt[k*16+c];
            v[c] = fin(ag[c] + r);
        }
        ln_act16(v, s2g, s2b, tupd);
    }
    #pragma unroll
    for (int j=0;j<48;j++) vals[j] = fin(vals[j]);
    #pragma unroll
    for (int g=0; g<16; g++){
        if (i == sptr[g]){
            for (int j=0;j<48;j++) stf(out, g*96+j, vals[j], isbf);
        }
    }
    int gi = b_tasks[i];
    int g0 = b_tasks[blockIdx.x*256];
    if (gi != g0) s_nonuni = 1;
    __syncthreads();
    if (s_nonuni){
        // fallback (not expected: 16384 nodes/graph is 256-divisible)
        for (int j=0;j<48;j++) atomicAdd(&pool_sums[gi*48+j], vals[j]);
        atomicAdd(&pool_cnt[gi], 1.f);
    } else {
        int lane = t & 63, wid = t >> 6;
        #pragma unroll
        for (int j=0;j<48;j++){
            float v = vals[j];
            v += __shfl_down(v, 32);
            v += __shfl_down(v, 16);
            v += __shfl_down(v, 8);
            v += __shfl_down(v, 4);
            v += __shfl_down(v, 2);
            v += __shfl_down(v, 1);
            if (lane==0) swave[wid*48+j] = v;
        }
        __syncthreads();
        if (t < 48){
            float s = swave[t] + swave[48+t] + swave[96+t] + swave[144+t];
            atomicAdd(&pool_sums[g0*48+t], s);
        }
        if (t == 0) atomicAdd(&pool_cnt[g0], 256.f);
    }
}

__global__ void finish_kernel(const float* __restrict__ sums, const float* __restrict__ cnt,
                              void* __restrict__ out, const int* __restrict__ flag)
{
    int t = threadIdx.x;
    if (t >= 768) return;
    int g = t/48, c = t - g*48;
    stf(out, g*96+48+c, fin(sums[g*48+c]/fmaxf(cnt[g],1.f)), *flag);
}

extern "C" void kernel_launch(void* const* d_in, const int* in_sizes, int n_in,
                              void* d_out, int out_size, void* d_ws, size_t ws_size,
                              hipStream_t stream)
{
    const void* x_tasks  = d_in[0];
    const void* x_data   = d_in[1];
    const void* stem_t_W = d_in[2];
    const void* stem_t_b = d_in[3];
    const void* stem_d_W = d_in[4];
    const void* stem_d_b = d_in[5];
    const void* ln_t_g   = d_in[6];
    const void* ln_t_b   = d_in[7];
    const void* ln_d_g   = d_in[8];
    const void* ln_d_b   = d_in[9];
    const void* dt_Wl    = d_in[10];
    const void* dt_Wr    = d_in[11];
    const void* dt_att   = d_in[12];
    const void* dt_res   = d_in[13];
    const void* dt_bias  = d_in[14];
    const void* tt_Wl    = d_in[15];
    const void* tt_Wr    = d_in[16];
    const void* tt_att   = d_in[17];
    const void* tt_res   = d_in[18];
    const void* tt_bias  = d_in[19];
    const void* ln1_g    = d_in[20];
    const void* ln1_b    = d_in[21];
    const void* ln2_g    = d_in[22];
    const void* ln2_b    = d_in[23];
    const int*  ei_dt    = (const int*)d_in[24];
    const int*  mask_dt  = (const int*)d_in[25];
    const int*  ei_tt    = (const int*)d_in[26];
    const int*  b_tasks  = (const int*)d_in[27];
    const int*  ptrg     = (const int*)d_in[28];

    char* w = (char*)d_ws;
    const size_t MB = 1ull<<20;
    float* xt        = (float*)(w);             // 16 MB  [NT,16]
    float* xl        = (float*)(w + 16*MB);     // 32 MB  [N,32]
    float* xr        = (float*)(w + 48*MB);     // 32 MB  [NT,32]
    float* agg_dt    = (float*)(w + 80*MB);     // 16 MB  [NT,16]
    float* agg_tt    = (float*)(w + 96*MB);     // 16 MB
    int*   offs      = (int*)  (w + 112*MB);    // (NT+1) ints
    int*   cursor    = (int*)  (w + 114*MB);    // NT ints (counts, then cursors)
    int*   esrc      = (int*)  (w + 116*MB);    // up to EDT ints (8 MB)
    float* pool_sums = (float*)(w + 124*MB);    // 768 floats
    float* pool_cnt  = (float*)(w + 124*MB + 4096);
    int*   flag      = (int*)  (w + 124*MB + 8192);
    int*   bsum      = (int*)  (w + 124*MB + 12288);  // 1024 ints

    detect_kernel<<<1, 256, 0, stream>>>((const unsigned*)x_tasks, flag);

    // pool accumulators; flag (at +8192) untouched
    hipMemsetAsync(w + 124*MB, 0, 8192, stream);

    // stems (task stem fused with @dt_Wr)
    stem_task_kernel<<<NT/256, 256, 0, stream>>>(x_tasks, stem_t_W, stem_t_b, ln_t_g, ln_t_b,
                                                 dt_Wr, xt, xr, flag);
    stem_data_transform_kernel<<<ND/256, 256, 0, stream>>>(x_data, stem_d_W, stem_d_b,
                                                           ln_d_g, ln_d_b, dt_Wl, xl, flag);
    // ---- d2t GAT ----
    hipMemsetAsync(cursor, 0, NT*sizeof(int), stream);
    hist_kernel<<<EDT/256, 256, 0, stream>>>(ei_dt, mask_dt, cursor, EDT);
    scan1_kernel<<<NT/65536*256, 256, 0, stream>>>(cursor, bsum);  // 1024 blocks
    scan2_kernel<<<1, 1024, 0, stream>>>(bsum);
    scan3_kernel<<<NT/256, 256, 0, stream>>>(cursor, bsum, offs);
    scatter_kernel<<<EDT/256, 256, 0, stream>>>(ei_dt, mask_dt, cursor, esrc, EDT);
    aggregate_kernel<<<NT/256, 256, 0, stream>>>(offs, esrc, xl, xr, dt_att, agg_dt, flag);

    // ---- t2t GAT (reuse xl/xr/CSR buffers) ----
    transform2_kernel<<<NT/256, 256, 0, stream>>>(xt, tt_Wl, tt_Wr, xl, xr, flag);
    hipMemsetAsync(cursor, 0, NT*sizeof(int), stream);
    hist_kernel<<<ETT/256, 256, 0, stream>>>(ei_tt, nullptr, cursor, ETT);
    scan1_kernel<<<NT/65536*256, 256, 0, stream>>>(cursor, bsum);
    scan2_kernel<<<1, 1024, 0, stream>>>(bsum);
    scan3_kernel<<<NT/256, 256, 0, stream>>>(cursor, bsum, offs);
    scatter_kernel<<<ETT/256, 256, 0, stream>>>(ei_tt, nullptr, cursor, esrc, ETT);
    aggregate_kernel<<<NT/256, 256, 0, stream>>>(offs, esrc, xl, xr, tt_att, agg_tt, flag);

    // fuse + pool + output
    fuse_pool_kernel<<<NT/256, 256, 0, stream>>>(xt, agg_dt, agg_tt,
        dt_res, dt_bias, tt_res, tt_bias, ln1_g, ln1_b, ln2_g, ln2_b,
        b_tasks, ptrg, pool_sums, pool_cnt, d_out, flag);
    finish_kernel<<<1, 768, 0, stream>>>(pool_sums, pool_cnt, d_out, flag);
}

// Round 7
// 572.652 us; speedup vs baseline: 6.8794x; 1.0320x over previous
//
#include <hip/hip_runtime.h>
#include <hip/hip_bf16.h>

typedef __hip_bfloat16 bf16;

#define NT 262144
#define ND 262144
#define EDT 2097152
#define ETT 1048576
#define NSLOT (2*NT)          // merged dst-slot space: [0,NT)=d2t, [NT,2NT)=tt
#define NBLK_SLOT (NSLOT/256) // 2048
#define NBLK_EDGE ((EDT+ETT)/256)

// ---- dual-dtype load/store: isbf==1 -> bf16, else fp32 ----
__device__ __forceinline__ float ldf(const void* p, long i, int isbf){
    if (isbf) return __bfloat162float(((const bf16*)p)[i]);
    return ((const float*)p)[i];
}
__device__ __forceinline__ void stf(void* p, int i, float v, int isbf){
    if (isbf) ((bf16*)p)[i] = __float2bfloat16(v);
    else      ((float*)p)[i] = v;
}
__device__ __forceinline__ float fin(float x){
    return (x==x && x>-3e38f && x<3e38f) ? x : 0.f;
}

// ---- input dtype detection: low-16-bit exponent census (see R2 notes) ----
__global__ void detect_kernel(const unsigned* __restrict__ raw, int* __restrict__ flag){
    __shared__ int cnt;
    if (threadIdx.x==0) cnt = 0;
    __syncthreads();
    int c = 0;
    for (int i = threadIdx.x; i < 2048; i += 256){
        unsigned w = raw[i];
        unsigned e = (w >> 7) & 0xFFu;
        if (e >= 116u && e <= 134u) c++;
    }
    atomicAdd(&cnt, c);
    __syncthreads();
    if (threadIdx.x==0) *flag = (cnt > 1024) ? 1 : 0;
}

// ---------------- task stem: x_tasks -> xt[NT,16], fused @tt_Wl -> xl_tt[NT,32] ----------------
__global__ __launch_bounds__(256) void stem_task_kernel(
    const void* __restrict__ x, const void* __restrict__ W, const void* __restrict__ bias,
    const void* __restrict__ lng, const void* __restrict__ lnb,
    const void* __restrict__ Wl_tt, float* __restrict__ xt, float* __restrict__ xl_tt,
    const int* __restrict__ flag)
{
    int isbf = *flag;
    __shared__ float sW[192], sb[16], sg[16], sbt[16], sWl[512];
    int t = threadIdx.x;
    if (t < 192) sW[t] = ldf(W, t, isbf);
    if (t < 16){ sb[t]=ldf(bias,t,isbf); sg[t]=ldf(lng,t,isbf); sbt[t]=ldf(lnb,t,isbf); }
    sWl[t]     = ldf(Wl_tt, t,     isbf);
    sWl[t+256] = ldf(Wl_tt, t+256, isbf);
    __syncthreads();
    long i = blockIdx.x*256 + t;
    float f[12];
    #pragma unroll
    for (int k=0;k<12;k++) f[k] = ldf(x, i*12+k, isbf);
    float h[16];
    #pragma unroll
    for (int c=0;c<16;c++){
        float a = sb[c];
        #pragma unroll
        for (int k=0;k<12;k++) a += f[k]*sW[k*16+c];
        h[c]=a;
    }
    float mu=0.f;
    #pragma unroll
    for (int c=0;c<16;c++) mu += h[c];
    mu *= (1.f/16.f);
    float var=0.f;
    #pragma unroll
    for (int c=0;c<16;c++){ float d=h[c]-mu; var += d*d; }
    var *= (1.f/16.f);
    float inv = rsqrtf(var + 1e-5f);
    float v[16];
    #pragma unroll
    for (int c=0;c<16;c++){
        float y = sg[c]*(h[c]-mu)*inv + sbt[c];
        v[c] = fin((y>0.f) ? y : 0.01f*y);
    }
    float4* xp = (float4*)(xt + i*16);
    #pragma unroll
    for (int q=0;q<4;q++) xp[q] = make_float4(v[q*4],v[q*4+1],v[q*4+2],v[q*4+3]);
    float o[32];
    #pragma unroll
    for (int c=0;c<32;c++) o[c]=0.f;
    #pragma unroll
    for (int k=0;k<16;k++){
        float xv=v[k];
        #pragma unroll
        for (int c=0;c<32;c++) o[c] += xv*sWl[k*32+c];
    }
    float4* op = (float4*)(xl_tt + i*32);
    #pragma unroll
    for (int q=0;q<8;q++)
        op[q] = make_float4(fin(o[q*4]),fin(o[q*4+1]),fin(o[q*4+2]),fin(o[q*4+3]));
}

// data stem fused with @dt_Wl -> xl_dt[ND,32]
__global__ __launch_bounds__(256) void stem_data_transform_kernel(
    const void* __restrict__ x, const void* __restrict__ W, const void* __restrict__ bias,
    const void* __restrict__ lng, const void* __restrict__ lnb,
    const void* __restrict__ Wl, float* __restrict__ xl,
    const int* __restrict__ flag)
{
    int isbf = *flag;
    __shared__ float sW[80], sb[16], sg[16], sbt[16], sWl[512];
    int t = threadIdx.x;
    if (t < 80) sW[t] = ldf(W, t, isbf);
    if (t < 16){ sb[t]=ldf(bias,t,isbf); sg[t]=ldf(lng,t,isbf); sbt[t]=ldf(lnb,t,isbf); }
    sWl[t]     = ldf(Wl, t,     isbf);
    sWl[t+256] = ldf(Wl, t+256, isbf);
    __syncthreads();
    long i = blockIdx.x*256 + t;
    float f[5];
    #pragma unroll
    for (int k=0;k<5;k++) f[k] = ldf(x, i*5+k, isbf);
    float h[16];
    #pragma unroll
    for (int c=0;c<16;c++){
        float a = sb[c];
        #pragma unroll
        for (int k=0;k<5;k++) a += f[k]*sW[k*16+c];
        h[c]=a;
    }
    float mu=0.f;
    #pragma unroll
    for (int c=0;c<16;c++) mu += h[c];
    mu *= (1.f/16.f);
    float var=0.f;
    #pragma unroll
    for (int c=0;c<16;c++){ float d=h[c]-mu; var += d*d; }
    var *= (1.f/16.f);
    float inv = rsqrtf(var + 1e-5f);
    float v[16];
    #pragma unroll
    for (int c=0;c<16;c++){
        float y = sg[c]*(h[c]-mu)*inv + sbt[c];
        v[c] = (y>0.f) ? y : 0.01f*y;
    }
    float o[32];
    #pragma unroll
    for (int c=0;c<32;c++) o[c]=0.f;
    #pragma unroll
    for (int k=0;k<16;k++){
        float xv=v[k];
        #pragma unroll
        for (int c=0;c<32;c++) o[c] += xv*sWl[k*32+c];
    }
    float4* op = (float4*)(xl + i*32);
    #pragma unroll
    for (int q=0;q<8;q++)
        op[q] = make_float4(fin(o[q*4]),fin(o[q*4+1]),fin(o[q*4+2]),fin(o[q*4+3]));
}

// ---------------- merged CSR build over both graphs ----------------
__global__ __launch_bounds__(256) void hist_both_kernel(
    const int* __restrict__ ei_dt, const int* __restrict__ mask_dt,
    const int* __restrict__ ei_tt, int* __restrict__ cnt)
{
    int e = blockIdx.x*256 + threadIdx.x;
    if (e < EDT){
        if (mask_dt[e]==0) return;
        atomicAdd(&cnt[ei_dt[EDT+e]], 1);
    } else {
        int e2 = e - EDT;
        atomicAdd(&cnt[NT + ei_tt[ETT+e2]], 1);
    }
}

// stage 1: per-256-chunk sums -> bsum[NBLK_SLOT] (grid must be NBLK_SLOT = 2048!)
__global__ __launch_bounds__(256) void scan1_kernel(const int* __restrict__ cnt, int* __restrict__ bsum)
{
    __shared__ int red[256];
    int t = threadIdx.x;
    red[t] = cnt[blockIdx.x*256 + t];
    __syncthreads();
    for (int s=128; s>0; s>>=1){
        if (t < s) red[t] += red[t+s];
        __syncthreads();
    }
    if (t==0) bsum[blockIdx.x] = red[0];
}
// stage 2: exclusive scan of 2048 block sums (single block, 2/thread)
__global__ __launch_bounds__(1024) void scan2_kernel(int* __restrict__ bsum)
{
    __shared__ int part[1024];
    int t = threadIdx.x;
    int a = bsum[2*t], b = bsum[2*t+1];
    int v = a + b;
    part[t] = v;
    __syncthreads();
    for (int off=1; off<1024; off<<=1){
        int x = part[t];
        int add = (t>=off) ? part[t-off] : 0;
        __syncthreads();
        part[t] = x + add;
        __syncthreads();
    }
    int ex = part[t] - v;
    bsum[2*t]   = ex;
    bsum[2*t+1] = ex + a;
}
// stage 3: local exclusive scan + block offset; writes offs[0..NSLOT] and cursors in place
__global__ __launch_bounds__(256) void scan3_kernel(
    int* __restrict__ cnt, const int* __restrict__ bsum, int* __restrict__ offs)
{
    __shared__ int part[256];
    int t = threadIdx.x;
    int i = blockIdx.x*256 + t;
    int v = cnt[i];
    part[t] = v;
    __syncthreads();
    for (int off=1; off<256; off<<=1){
        int x = part[t];
        int add = (t>=off) ? part[t-off] : 0;
        __syncthreads();
        part[t] = x + add;
        __syncthreads();
    }
    int ex = part[t] - v + bsum[blockIdx.x];
    offs[i] = ex;
    cnt[i]  = ex;   // scatter cursor
    if (blockIdx.x == gridDim.x-1 && t == 255) offs[NSLOT] = ex + v;
}

__global__ __launch_bounds__(256) void scatter_both_kernel(
    const int* __restrict__ ei_dt, const int* __restrict__ mask_dt,
    const int* __restrict__ ei_tt,
    int* __restrict__ cursor, int* __restrict__ esrc)
{
    int e = blockIdx.x*256 + threadIdx.x;
    int s, slot;
    if (e < EDT){
        if (mask_dt[e]==0) return;
        s = ei_dt[e]; slot = ei_dt[EDT+e];
    } else {
        int e2 = e - EDT;
        s = ei_tt[e2]; slot = NT + ei_tt[ETT+e2];
    }
    int pos = atomicAdd(&cursor[slot], 1);
    __builtin_nontemporal_store(s, &esrc[pos]);
}

// ---------------- dst-centric GAT aggregation, both graphs, on-the-fly xr ----------------
__global__ __launch_bounds__(256) void aggregate_both_kernel(
    const int* __restrict__ offs, const int* __restrict__ esrc,
    const float* __restrict__ xt,
    const float* __restrict__ xl_dt, const float* __restrict__ xl_tt,
    const void* __restrict__ dt_Wr, const void* __restrict__ tt_Wr,
    const void* __restrict__ dt_att, const void* __restrict__ tt_att,
    float* __restrict__ agg, const int* __restrict__ flag)
{
    int isbf = *flag;
    __shared__ float sWr[512], satt[32];
    int t = threadIdx.x;
    int which = (blockIdx.x >= NT/256);   // 0 = dt, 1 = tt (block-uniform)
    const void* Wr  = which ? tt_Wr  : dt_Wr;
    const void* att = which ? tt_att : dt_att;
    sWr[t]     = ldf(Wr, t,     isbf);
    sWr[t+256] = ldf(Wr, t+256, isbf);
    if (t < 32) satt[t] = ldf(att, t, isbf);
    __syncthreads();
    long gid = (long)blockIdx.x*256 + t;          // slot id in [0, NSLOT)
    long d   = which ? gid - NT : gid;            // dst node id
    const float* xl = which ? xl_tt : xl_dt;
    const float4* xp = (const float4*)(xt + d*16);
    float4 x0=xp[0], x1=xp[1], x2=xp[2], x3=xp[3];
    float xtv[16] = {x0.x,x0.y,x0.z,x0.w, x1.x,x1.y,x1.z,x1.w,
                     x2.x,x2.y,x2.z,x2.w, x3.x,x3.y,x3.z,x3.w};
    float xrv[32];
    #pragma unroll
    for (int c=0;c<32;c++) xrv[c]=0.f;
    #pragma unroll
    for (int k=0;k<16;k++){
        float xv=xtv[k];
        #pragma unroll
        for (int c=0;c<32;c++) xrv[c] += xv*sWr[k*32+c];
    }
    float acc[32];
    #pragma unroll
    for (int c=0;c<32;c++) acc[c]=0.f;
    float den0=0.f, den1=0.f;
    int e0 = offs[gid], e1 = offs[gid+1];
    for (int e=e0; e<e1; e++){
        long s = esrc[e];
        const float4* a4 = (const float4*)(xl + s*32);
        float xs[32];
        float sc0=0.f, sc1=0.f;
        #pragma unroll
        for (int q=0;q<8;q++){
            float4 a = a4[q];
            xs[q*4]=a.x; xs[q*4+1]=a.y; xs[q*4+2]=a.z; xs[q*4+3]=a.w;
            float m0=a.x+xrv[q*4], m1=a.y+xrv[q*4+1], m2=a.z+xrv[q*4+2], m3=a.w+xrv[q*4+3];
            m0 = m0>0.f?m0:0.2f*m0; m1 = m1>0.f?m1:0.2f*m1;
            m2 = m2>0.f?m2:0.2f*m2; m3 = m3>0.f?m3:0.2f*m3;
            float p = m0*satt[q*4] + m1*satt[q*4+1] + m2*satt[q*4+2] + m3*satt[q*4+3];
            if (q < 4) sc0 += p; else sc1 += p;
        }
        float a0 = expf(fminf(fin(sc0), 60.f));
        float a1 = expf(fminf(fin(sc1), 60.f));
        den0 += a0; den1 += a1;
        #pragma unroll
        for (int c=0;c<16;c++){
            acc[c]    += a0*xs[c];
            acc[16+c] += a1*xs[16+c];
        }
    }
    float id0 = 1.f/fmaxf(den0, 1e-16f);
    float id1 = 1.f/fmaxf(den1, 1e-16f);
    float4* op = (float4*)(agg + gid*16);
    #pragma unroll
    for (int q=0;q<4;q++){
        op[q] = make_float4(
            fin(0.5f*(acc[q*4  ]*id0 + acc[16+q*4  ]*id1)),
            fin(0.5f*(acc[q*4+1]*id0 + acc[16+q*4+1]*id1)),
            fin(0.5f*(acc[q*4+2]*id0 + acc[16+q*4+2]*id1)),
            fin(0.5f*(acc[q*4+3]*id0 + acc[16+q*4+3]*id1)));
    }
}

__device__ __forceinline__ void ln_act16(const float* v, const float* g, const float* b, float* o){
    float mu=0.f;
    #pragma unroll
    for (int c=0;c<16;c++) mu += v[c];
    mu *= (1.f/16.f);
    float var=0.f;
    #pragma unroll
    for (int c=0;c<16;c++){ float d=v[c]-mu; var += d*d; }
    var *= (1.f/16.f);
    float inv = rsqrtf(var + 1e-5f);
    #pragma unroll
    for (int c=0;c<16;c++){
        float y = g[c]*(v[c]-mu)*inv + b[c];
        o[c] = (y>0.f) ? y : 0.01f*y;
    }
}

// ---------------- fuse + pooling (wave-shuffle reduction) ----------------
__global__ __launch_bounds__(256) void fuse_pool_kernel(
    const float* __restrict__ xt,
    const float* __restrict__ agg_dt, const float* __restrict__ agg_tt,
    const void* __restrict__ dt_res, const void* __restrict__ dt_bias,
    const void* __restrict__ tt_res, const void* __restrict__ tt_bias,
    const void* __restrict__ ln1g, const void* __restrict__ ln1b,
    const void* __restrict__ ln2g, const void* __restrict__ ln2b,
    const int* __restrict__ b_tasks, const int* __restrict__ ptrg,
    float* __restrict__ pool_sums, float* __restrict__ pool_cnt,
    void* __restrict__ out, const int* __restrict__ flag)
{
    int isbf = *flag;
    __shared__ float sdt[256], stt[256], sdb[16], stb[16], s1g[16], s1b[16], s2g[16], s2b[16];
    __shared__ float swave[4*48];
    __shared__ int sptr[16];
    __shared__ int s_nonuni;
    int t = threadIdx.x;
    sdt[t] = ldf(dt_res, t, isbf);
    stt[t] = ldf(tt_res, t, isbf);
    if (t < 16){
        sdb[t]=ldf(dt_bias,t,isbf); stb[t]=ldf(tt_bias,t,isbf);
        s1g[t]=ldf(ln1g,t,isbf); s1b[t]=ldf(ln1b,t,isbf);
        s2g[t]=ldf(ln2g,t,isbf); s2b[t]=ldf(ln2b,t,isbf);
        sptr[t]=ptrg[t];
    }
    if (t==0) s_nonuni = 0;
    __syncthreads();
    long i = blockIdx.x*256 + t;
    const float4* xp = (const float4*)(xt + i*16);
    float4 x0=xp[0], x1=xp[1], x2=xp[2], x3=xp[3];
    float vals[48];
    float* xv   = vals;
    float* tupd = vals+16;
    float* dupd = vals+32;
    xv[0]=x0.x; xv[1]=x0.y; xv[2]=x0.z; xv[3]=x0.w;
    xv[4]=x1.x; xv[5]=x1.y; xv[6]=x1.z; xv[7]=x1.w;
    xv[8]=x2.x; xv[9]=x2.y; xv[10]=x2.z; xv[11]=x2.w;
    xv[12]=x3.x; xv[13]=x3.y; xv[14]=x3.z; xv[15]=x3.w;
    {
        const float* ag = agg_dt + i*16;
        float v[16];
        #pragma unroll
        for (int c=0;c<16;c++){
            float r = sdb[c];
            #pragma unroll
            for (int k=0;k<16;k++) r += xv[k]*sdt[k*16+c];
            v[c] = fin(ag[c] + r);
        }
        ln_act16(v, s1g, s1b, dupd);
    }
    {
        const float* ag = agg_tt + i*16;
        float v[16];
        #pragma unroll
        for (int c=0;c<16;c++){
            float r = stb[c];
            #pragma unroll
            for (int k=0;k<16;k++) r += xv[k]*stt[k*16+c];
            v[c] = fin(ag[c] + r);
        }
        ln_act16(v, s2g, s2b, tupd);
    }
    #pragma unroll
    for (int j=0;j<48;j++) vals[j] = fin(vals[j]);
    #pragma unroll
    for (int g=0; g<16; g++){
        if (i == sptr[g]){
            for (int j=0;j<48;j++) stf(out, g*96+j, vals[j], isbf);
        }
    }
    int gi = b_tasks[i];
    int g0 = b_tasks[blockIdx.x*256];
    if (gi != g0) s_nonuni = 1;
    __syncthreads();
    if (s_nonuni){
        for (int j=0;j<48;j++) atomicAdd(&pool_sums[gi*48+j], vals[j]);
        atomicAdd(&pool_cnt[gi], 1.f);
    } else {
        int lane = t & 63, wid = t >> 6;
        #pragma unroll
        for (int j=0;j<48;j++){
            float v = vals[j];
            v += __shfl_down(v, 32);
            v += __shfl_down(v, 16);
            v += __shfl_down(v, 8);
            v += __shfl_down(v, 4);
            v += __shfl_down(v, 2);
            v += __shfl_down(v, 1);
            if (lane==0) swave[wid*48+j] = v;
        }
        __syncthreads();
        if (t < 48){
            float s = swave[t] + swave[48+t] + swave[96+t] + swave[144+t];
            atomicAdd(&pool_sums[g0*48+t], s);
        }
        if (t == 0) atomicAdd(&pool_cnt[g0], 256.f);
    }
}

__global__ void finish_kernel(const float* __restrict__ sums, const float* __restrict__ cnt,
                              void* __restrict__ out, const int* __restrict__ flag)
{
    int t = threadIdx.x;
    if (t >= 768) return;
    int g = t/48, c = t - g*48;
    stf(out, g*96+48+c, fin(sums[g*48+c]/fmaxf(cnt[g],1.f)), *flag);
}

extern "C" void kernel_launch(void* const* d_in, const int* in_sizes, int n_in,
                              void* d_out, int out_size, void* d_ws, size_t ws_size,
                              hipStream_t stream)
{
    const void* x_tasks  = d_in[0];
    const void* x_data   = d_in[1];
    const void* stem_t_W = d_in[2];
    const void* stem_t_b = d_in[3];
    const void* stem_d_W = d_in[4];
    const void* stem_d_b = d_in[5];
    const void* ln_t_g   = d_in[6];
    const void* ln_t_b   = d_in[7];
    const void* ln_d_g   = d_in[8];
    const void* ln_d_b   = d_in[9];
    const void* dt_Wl    = d_in[10];
    const void* dt_Wr    = d_in[11];
    const void* dt_att   = d_in[12];
    const void* dt_res   = d_in[13];
    const void* dt_bias  = d_in[14];
    const void* tt_Wl    = d_in[15];
    const void* tt_Wr    = d_in[16];
    const void* tt_att   = d_in[17];
    const void* tt_res   = d_in[18];
    const void* tt_bias  = d_in[19];
    const void* ln1_g    = d_in[20];
    const void* ln1_b    = d_in[21];
    const void* ln2_g    = d_in[22];
    const void* ln2_b    = d_in[23];
    const int*  ei_dt    = (const int*)d_in[24];
    const int*  mask_dt  = (const int*)d_in[25];
    const int*  ei_tt    = (const int*)d_in[26];
    const int*  b_tasks  = (const int*)d_in[27];
    const int*  ptrg     = (const int*)d_in[28];

    char* w = (char*)d_ws;
    const size_t MB = 1ull<<20;
    float* xt        = (float*)(w);              // 16 MB  [NT,16]
    float* xl_dt     = (float*)(w + 16*MB);      // 32 MB  [ND,32]
    float* xl_tt     = (float*)(w + 48*MB);      // 32 MB  [NT,32]
    float* agg       = (float*)(w + 80*MB);      // 32 MB  [NSLOT,16] (dt then tt)
    int*   cnt       = (int*)  (w + 112*MB);     // 2 MB   [NSLOT] counts->cursors
    float* pool_sums = (float*)(w + 114*MB);     // 768 floats
    float* pool_cnt  = (float*)(w + 114*MB + 4096);
    int*   offs      = (int*)  (w + 115*MB);     // NSLOT+1 ints (2 MB + 4)
    int*   esrc      = (int*)  (w + 118*MB);     // up to 3M ints (12 MB)
    int*   flag      = (int*)  (w + 130*MB);
    int*   bsum      = (int*)  (w + 130*MB + 4096);  // NBLK_SLOT=2048 ints

    detect_kernel<<<1, 256, 0, stream>>>((const unsigned*)x_tasks, flag);

    // zero: cnt (2 MB) + pool accumulators (8 KB) in one contiguous memset
    hipMemsetAsync(w + 112*MB, 0, 2*MB + 8192, stream);

    // stems (task stem fused with @tt_Wl; data stem fused with @dt_Wl)
    stem_task_kernel<<<NT/256, 256, 0, stream>>>(x_tasks, stem_t_W, stem_t_b, ln_t_g, ln_t_b,
                                                 tt_Wl, xt, xl_tt, flag);
    stem_data_transform_kernel<<<ND/256, 256, 0, stream>>>(x_data, stem_d_W, stem_d_b,
                                                           ln_d_g, ln_d_b, dt_Wl, xl_dt, flag);
    // merged CSR build over both graphs
    hist_both_kernel<<<NBLK_EDGE, 256, 0, stream>>>(ei_dt, mask_dt, ei_tt, cnt);
    scan1_kernel<<<NBLK_SLOT, 256, 0, stream>>>(cnt, bsum);   // 2048 blocks (R6 bug: was 8)
    scan2_kernel<<<1, 1024, 0, stream>>>(bsum);
    scan3_kernel<<<NBLK_SLOT, 256, 0, stream>>>(cnt, bsum, offs);
    scatter_both_kernel<<<NBLK_EDGE, 256, 0, stream>>>(ei_dt, mask_dt, ei_tt, cnt, esrc);

    // merged aggregation (on-the-fly xr from xt)
    aggregate_both_kernel<<<NBLK_SLOT, 256, 0, stream>>>(offs, esrc, xt, xl_dt, xl_tt,
        dt_Wr, tt_Wr, dt_att, tt_att, agg, flag);

    // fuse + pool + output
    fuse_pool_kernel<<<NT/256, 256, 0, stream>>>(xt, agg, agg + (long)NT*16,
        dt_res, dt_bias, tt_res, tt_bias, ln1_g, ln1_b, ln2_g, ln2_b,
        b_tasks, ptrg, pool_sums, pool_cnt, d_out, flag);
    finish_kernel<<<1, 768, 0, stream>>>(pool_sums, pool_cnt, d_out, flag);
}

// Round 8
// 480.154 us; speedup vs baseline: 8.2046x; 1.1926x over previous
//
#include <hip/hip_runtime.h>
#include <hip/hip_bf16.h>

typedef __hip_bfloat16 bf16;

#define NT 262144
#define ND 262144
#define EDT 2097152
#define ETT 1048576
#define NSLOT (2*NT)            // [0,NT)=d2t dst slots, [NT,2NT)=tt dst slots
#define NE_TOT (EDT+ETT)        // 3145728
#define NBKT 1024               // coarse buckets, bucket = slot>>9
#define SPB 512                 // slots per bucket
#define BCAP 3072               // per-bucket ebuf capacity (mean ~2048, +22 sigma)
#define CH 16384                // edges per phase-1 block
#define NBLK1 (NE_TOT/CH)       // 192

// ---- dual-dtype load/store: isbf==1 -> bf16, else fp32 ----
__device__ __forceinline__ float ldf(const void* p, long i, int isbf){
    if (isbf) return __bfloat162float(((const bf16*)p)[i]);
    return ((const float*)p)[i];
}
__device__ __forceinline__ void stf(void* p, int i, float v, int isbf){
    if (isbf) ((bf16*)p)[i] = __float2bfloat16(v);
    else      ((float*)p)[i] = v;
}
__device__ __forceinline__ float fin(float x){
    return (x==x && x>-3e38f && x<3e38f) ? x : 0.f;
}

// ---- input dtype detection: low-16-bit exponent census (see R2 notes) ----
__global__ void detect_kernel(const unsigned* __restrict__ raw, int* __restrict__ flag){
    __shared__ int cnt;
    if (threadIdx.x==0) cnt = 0;
    __syncthreads();
    int c = 0;
    for (int i = threadIdx.x; i < 2048; i += 256){
        unsigned w = raw[i];
        unsigned e = (w >> 7) & 0xFFu;
        if (e >= 116u && e <= 134u) c++;
    }
    atomicAdd(&cnt, c);
    __syncthreads();
    if (threadIdx.x==0) *flag = (cnt > 1024) ? 1 : 0;
}

__global__ void init_cursors_kernel(int* __restrict__ bktCur){
    int i = blockIdx.x*256 + threadIdx.x;
    if (i < NBKT) bktCur[i] = i*BCAP;
}

// ---------------- task stem: x_tasks -> xt[NT,16], fused @tt_Wl -> xl_tt[NT,32] ----------------
__global__ __launch_bounds__(256) void stem_task_kernel(
    const void* __restrict__ x, const void* __restrict__ W, const void* __restrict__ bias,
    const void* __restrict__ lng, const void* __restrict__ lnb,
    const void* __restrict__ Wl_tt, float* __restrict__ xt, float* __restrict__ xl_tt,
    const int* __restrict__ flag)
{
    int isbf = *flag;
    __shared__ float sW[192], sb[16], sg[16], sbt[16], sWl[512];
    int t = threadIdx.x;
    if (t < 192) sW[t] = ldf(W, t, isbf);
    if (t < 16){ sb[t]=ldf(bias,t,isbf); sg[t]=ldf(lng,t,isbf); sbt[t]=ldf(lnb,t,isbf); }
    sWl[t]     = ldf(Wl_tt, t,     isbf);
    sWl[t+256] = ldf(Wl_tt, t+256, isbf);
    __syncthreads();
    long i = blockIdx.x*256 + t;
    float f[12];
    #pragma unroll
    for (int k=0;k<12;k++) f[k] = ldf(x, i*12+k, isbf);
    float h[16];
    #pragma unroll
    for (int c=0;c<16;c++){
        float a = sb[c];
        #pragma unroll
        for (int k=0;k<12;k++) a += f[k]*sW[k*16+c];
        h[c]=a;
    }
    float mu=0.f;
    #pragma unroll
    for (int c=0;c<16;c++) mu += h[c];
    mu *= (1.f/16.f);
    float var=0.f;
    #pragma unroll
    for (int c=0;c<16;c++){ float d=h[c]-mu; var += d*d; }
    var *= (1.f/16.f);
    float inv = rsqrtf(var + 1e-5f);
    float v[16];
    #pragma unroll
    for (int c=0;c<16;c++){
        float y = sg[c]*(h[c]-mu)*inv + sbt[c];
        v[c] = fin((y>0.f) ? y : 0.01f*y);
    }
    float4* xp = (float4*)(xt + i*16);
    #pragma unroll
    for (int q=0;q<4;q++) xp[q] = make_float4(v[q*4],v[q*4+1],v[q*4+2],v[q*4+3]);
    float o[32];
    #pragma unroll
    for (int c=0;c<32;c++) o[c]=0.f;
    #pragma unroll
    for (int k=0;k<16;k++){
        float xv=v[k];
        #pragma unroll
        for (int c=0;c<32;c++) o[c] += xv*sWl[k*32+c];
    }
    float4* op = (float4*)(xl_tt + i*32);
    #pragma unroll
    for (int q=0;q<8;q++)
        op[q] = make_float4(fin(o[q*4]),fin(o[q*4+1]),fin(o[q*4+2]),fin(o[q*4+3]));
}

// data stem fused with @dt_Wl -> xl_dt[ND,32]
__global__ __launch_bounds__(256) void stem_data_transform_kernel(
    const void* __restrict__ x, const void* __restrict__ W, const void* __restrict__ bias,
    const void* __restrict__ lng, const void* __restrict__ lnb,
    const void* __restrict__ Wl, float* __restrict__ xl,
    const int* __restrict__ flag)
{
    int isbf = *flag;
    __shared__ float sW[80], sb[16], sg[16], sbt[16], sWl[512];
    int t = threadIdx.x;
    if (t < 80) sW[t] = ldf(W, t, isbf);
    if (t < 16){ sb[t]=ldf(bias,t,isbf); sg[t]=ldf(lng,t,isbf); sbt[t]=ldf(lnb,t,isbf); }
    sWl[t]     = ldf(Wl, t,     isbf);
    sWl[t+256] = ldf(Wl, t+256, isbf);
    __syncthreads();
    long i = blockIdx.x*256 + t;
    float f[5];
    #pragma unroll
    for (int k=0;k<5;k++) f[k] = ldf(x, i*5+k, isbf);
    float h[16];
    #pragma unroll
    for (int c=0;c<16;c++){
        float a = sb[c];
        #pragma unroll
        for (int k=0;k<5;k++) a += f[k]*sW[k*16+c];
        h[c]=a;
    }
    float mu=0.f;
    #pragma unroll
    for (int c=0;c<16;c++) mu += h[c];
    mu *= (1.f/16.f);
    float var=0.f;
    #pragma unroll
    for (int c=0;c<16;c++){ float d=h[c]-mu; var += d*d; }
    var *= (1.f/16.f);
    float inv = rsqrtf(var + 1e-5f);
    float v[16];
    #pragma unroll
    for (int c=0;c<16;c++){
        float y = sg[c]*(h[c]-mu)*inv + sbt[c];
        v[c] = (y>0.f) ? y : 0.01f*y;
    }
    float o[32];
    #pragma unroll
    for (int c=0;c<32;c++) o[c]=0.f;
    #pragma unroll
    for (int k=0;k<16;k++){
        float xv=v[k];
        #pragma unroll
        for (int c=0;c<32;c++) o[c] += xv*sWl[k*32+c];
    }
    float4* op = (float4*)(xl + i*32);
    #pragma unroll
    for (int q=0;q<8;q++)
        op[q] = make_float4(fin(o[q*4]),fin(o[q*4+1]),fin(o[q*4+2]),fin(o[q*4+3]));
}

// ---------------- phase 1: LDS-staged coarse bucket scatter ----------------
// packed edge: src (18 bits) | dloc=slot&511 (10 bits) << 18
__global__ __launch_bounds__(256) void bucket_scatter_kernel(
    const int* __restrict__ ei_dt, const int* __restrict__ mask_dt,
    const int* __restrict__ ei_tt,
    int* __restrict__ bktCur, unsigned* __restrict__ ebuf)
{
    __shared__ int shc[NBKT];      // counts, then reused as global run bases
    __shared__ int sloff[NBKT];    // exclusive offsets (stage layout)
    __shared__ int slcur[NBKT];    // placement cursors
    __shared__ int spart[256];
    __shared__ unsigned stage[CH]; // 64KB
    int t = threadIdx.x;
    long e0 = (long)blockIdx.x * CH;
    for (int b=t; b<NBKT; b+=256) shc[b]=0;
    __syncthreads();
    // pass A: histogram by bucket
    for (int i=t; i<CH; i+=256){
        long e = e0 + i;
        int slot, keep;
        if (e < EDT){ keep = mask_dt[e]; slot = ei_dt[EDT+e]; }
        else { long e2 = e-EDT; keep = 1; slot = NT + ei_tt[ETT+e2]; }
        if (keep) atomicAdd(&shc[slot>>9], 1);
    }
    __syncthreads();
    // scan 1024 counts (4 per thread)
    int b4 = t*4;
    int a0=shc[b4], a1=shc[b4+1], a2=shc[b4+2], a3=shc[b4+3];
    int lsum = a0+a1+a2+a3;
    spart[t] = lsum;
    __syncthreads();
    for (int off=1; off<256; off<<=1){
        int x = spart[t];
        int add = (t>=off) ? spart[t-off] : 0;
        __syncthreads();
        spart[t] = x + add;
        __syncthreads();
    }
    int run = spart[t] - lsum;
    int totKept = spart[255];
    sloff[b4]=run;            slcur[b4]=run;            run+=a0;
    sloff[b4+1]=run;          slcur[b4+1]=run;          run+=a1;
    sloff[b4+2]=run;          slcur[b4+2]=run;          run+=a2;
    sloff[b4+3]=run;          slcur[b4+3]=run;
    // reserve global runs (shc becomes run base)
    if (a0>0) shc[b4]   = atomicAdd(&bktCur[b4],   a0);
    if (a1>0) shc[b4+1] = atomicAdd(&bktCur[b4+1], a1);
    if (a2>0) shc[b4+2] = atomicAdd(&bktCur[b4+2], a2);
    if (a3>0) shc[b4+3] = atomicAdd(&bktCur[b4+3], a3);
    __syncthreads();
    // pass B: place packed edges into stage, ordered by bucket
    for (int i=t; i<CH; i+=256){
        long e = e0 + i;
        int slot, keep, s;
        if (e < EDT){ keep = mask_dt[e]; s = ei_dt[e]; slot = ei_dt[EDT+e]; }
        else { long e2 = e-EDT; keep = 1; s = ei_tt[e2]; slot = NT + ei_tt[ETT+e2]; }
        if (keep){
            int b = slot>>9;
            int pos = atomicAdd(&slcur[b], 1);
            stage[pos] = (unsigned)s | ((unsigned)(slot & 511) << 18);
        }
    }
    __syncthreads();
    // write-out: contiguous per-bucket runs (binary search bucket of stage idx)
    for (int i=t; i<totKept; i+=256){
        int lo=0, hi=NBKT-1;
        while (lo<hi){ int mid=(lo+hi+1)>>1; if (sloff[mid]<=i) lo=mid; else hi=mid-1; }
        ebuf[shc[lo] + (i - sloff[lo])] = stage[i];
    }
}

// ---------------- phase 2: per-bucket LDS CSR + GAT aggregation ----------------
__global__ __launch_bounds__(256) void bucket_aggregate_kernel(
    const int* __restrict__ bktCur, const unsigned* __restrict__ ebuf,
    const float* __restrict__ xt,
    const float* __restrict__ xl_dt, const float* __restrict__ xl_tt,
    const void* __restrict__ dt_Wr, const void* __restrict__ tt_Wr,
    const void* __restrict__ dt_att, const void* __restrict__ tt_att,
    float* __restrict__ agg, const int* __restrict__ flag)
{
    __shared__ float sWr[512], satt[32];
    __shared__ int scnt[SPB], soff[SPB], scur[SPB], spart[256];
    __shared__ unsigned slist[BCAP];   // 12KB
    int t = threadIdx.x;
    int b = blockIdx.x;
    int which = (b >= NBKT/2);         // buckets [0,512)=dt, [512,1024)=tt
    int isbf = *flag;
    const void* Wr  = which ? tt_Wr  : dt_Wr;
    const void* att = which ? tt_att : dt_att;
    sWr[t]     = ldf(Wr, t,     isbf);
    sWr[t+256] = ldf(Wr, t+256, isbf);
    if (t < 32) satt[t] = ldf(att, t, isbf);
    scnt[t] = 0; scnt[t+256] = 0;
    __syncthreads();
    int base = b*BCAP;
    int ecnt = bktCur[b] - base;
    if (ecnt > BCAP) ecnt = BCAP;
    if (ecnt < 0) ecnt = 0;
    // per-dst histogram
    for (int i=t; i<ecnt; i+=256)
        atomicAdd(&scnt[ebuf[base+i] >> 18], 1);
    __syncthreads();
    // scan 512 (2 per thread)
    int c0 = scnt[2*t], c1 = scnt[2*t+1];
    int ls = c0 + c1;
    spart[t] = ls;
    __syncthreads();
    for (int off=1; off<256; off<<=1){
        int x = spart[t];
        int add = (t>=off) ? spart[t-off] : 0;
        __syncthreads();
        spart[t] = x + add;
        __syncthreads();
    }
    int run = spart[t] - ls;
    soff[2*t] = run; scur[2*t] = run;
    soff[2*t+1] = run + c0; scur[2*t+1] = run + c0;
    __syncthreads();
    // place src ids into per-dst lists
    for (int i=t; i<ecnt; i+=256){
        unsigned p = ebuf[base+i];
        int pos = atomicAdd(&scur[p >> 18], 1);
        slist[pos] = p & 0x3FFFFu;
    }
    __syncthreads();
    // aggregate: 2 dsts per thread
    const float* xl = which ? xl_tt : xl_dt;
    for (int half=0; half<2; half++){
        int dloc = t + half*256;
        long slot = (long)b*SPB + dloc;
        long d = which ? slot - NT : slot;
        const float4* xp = (const float4*)(xt + d*16);
        float4 x0=xp[0], x1=xp[1], x2=xp[2], x3=xp[3];
        float xtv[16] = {x0.x,x0.y,x0.z,x0.w, x1.x,x1.y,x1.z,x1.w,
                         x2.x,x2.y,x2.z,x2.w, x3.x,x3.y,x3.z,x3.w};
        float xrv[32];
        #pragma unroll
        for (int c=0;c<32;c++) xrv[c]=0.f;
        #pragma unroll
        for (int k=0;k<16;k++){
            float xv=xtv[k];
            #pragma unroll
            for (int c=0;c<32;c++) xrv[c] += xv*sWr[k*32+c];
        }
        float acc[32];
        #pragma unroll
        for (int c=0;c<32;c++) acc[c]=0.f;
        float den0=0.f, den1=0.f;
        int e0 = soff[dloc], e1 = scur[dloc];   // scur = end after placement
        for (int e=e0; e<e1; e++){
            long s = slist[e];
            const float4* a4 = (const float4*)(xl + s*32);
            float xs[32];
            float sc0=0.f, sc1=0.f;
            #pragma unroll
            for (int q=0;q<8;q++){
                float4 a = a4[q];
                xs[q*4]=a.x; xs[q*4+1]=a.y; xs[q*4+2]=a.z; xs[q*4+3]=a.w;
                float m0=a.x+xrv[q*4], m1=a.y+xrv[q*4+1], m2=a.z+xrv[q*4+2], m3=a.w+xrv[q*4+3];
                m0 = m0>0.f?m0:0.2f*m0; m1 = m1>0.f?m1:0.2f*m1;
                m2 = m2>0.f?m2:0.2f*m2; m3 = m3>0.f?m3:0.2f*m3;
                float p = m0*satt[q*4] + m1*satt[q*4+1] + m2*satt[q*4+2] + m3*satt[q*4+3];
                if (q < 4) sc0 += p; else sc1 += p;
            }
            float a0 = expf(fminf(fin(sc0), 60.f));
            float a1 = expf(fminf(fin(sc1), 60.f));
            den0 += a0; den1 += a1;
            #pragma unroll
            for (int c=0;c<16;c++){
                acc[c]    += a0*xs[c];
                acc[16+c] += a1*xs[16+c];
            }
        }
        float id0 = 1.f/fmaxf(den0, 1e-16f);
        float id1 = 1.f/fmaxf(den1, 1e-16f);
        float4* op = (float4*)(agg + slot*16);
        #pragma unroll
        for (int q=0;q<4;q++){
            op[q] = make_float4(
                fin(0.5f*(acc[q*4  ]*id0 + acc[16+q*4  ]*id1)),
                fin(0.5f*(acc[q*4+1]*id0 + acc[16+q*4+1]*id1)),
                fin(0.5f*(acc[q*4+2]*id0 + acc[16+q*4+2]*id1)),
                fin(0.5f*(acc[q*4+3]*id0 + acc[16+q*4+3]*id1)));
        }
    }
}

__device__ __forceinline__ void ln_act16(const float* v, const float* g, const float* b, float* o){
    float mu=0.f;
    #pragma unroll
    for (int c=0;c<16;c++) mu += v[c];
    mu *= (1.f/16.f);
    float var=0.f;
    #pragma unroll
    for (int c=0;c<16;c++){ float d=v[c]-mu; var += d*d; }
    var *= (1.f/16.f);
    float inv = rsqrtf(var + 1e-5f);
    #pragma unroll
    for (int c=0;c<16;c++){
        float y = g[c]*(v[c]-mu)*inv + b[c];
        o[c] = (y>0.f) ? y : 0.01f*y;
    }
}

// ---------------- fuse + pooling (wave-shuffle reduction) ----------------
__global__ __launch_bounds__(256) void fuse_pool_kernel(
    const float* __restrict__ xt,
    const float* __restrict__ agg_dt, const float* __restrict__ agg_tt,
    const void* __restrict__ dt_res, const void* __restrict__ dt_bias,
    const void* __restrict__ tt_res, const void* __restrict__ tt_bias,
    const void* __restrict__ ln1g, const void* __restrict__ ln1b,
    const void* __restrict__ ln2g, const void* __restrict__ ln2b,
    const int* __restrict__ b_tasks, const int* __restrict__ ptrg,
    float* __restrict__ pool_sums, float* __restrict__ pool_cnt,
    void* __restrict__ out, const int* __restrict__ flag)
{
    int isbf = *flag;
    __shared__ float sdt[256], stt[256], sdb[16], stb[16], s1g[16], s1b[16], s2g[16], s2b[16];
    __shared__ float swave[4*48];
    __shared__ int sptr[16];
    __shared__ int s_nonuni;
    int t = threadIdx.x;
    sdt[t] = ldf(dt_res, t, isbf);
    stt[t] = ldf(tt_res, t, isbf);
    if (t < 16){
        sdb[t]=ldf(dt_bias,t,isbf); stb[t]=ldf(tt_bias,t,isbf);
        s1g[t]=ldf(ln1g,t,isbf); s1b[t]=ldf(ln1b,t,isbf);
        s2g[t]=ldf(ln2g,t,isbf); s2b[t]=ldf(ln2b,t,isbf);
        sptr[t]=ptrg[t];
    }
    if (t==0) s_nonuni = 0;
    __syncthreads();
    long i = blockIdx.x*256 + t;
    const float4* xp = (const float4*)(xt + i*16);
    float4 x0=xp[0], x1=xp[1], x2=xp[2], x3=xp[3];
    float vals[48];
    float* xv   = vals;
    float* tupd = vals+16;
    float* dupd = vals+32;
    xv[0]=x0.x; xv[1]=x0.y; xv[2]=x0.z; xv[3]=x0.w;
    xv[4]=x1.x; xv[5]=x1.y; xv[6]=x1.z; xv[7]=x1.w;
    xv[8]=x2.x; xv[9]=x2.y; xv[10]=x2.z; xv[11]=x2.w;
    xv[12]=x3.x; xv[13]=x3.y; xv[14]=x3.z; xv[15]=x3.w;
    {
        const float* ag = agg_dt + i*16;
        float v[16];
        #pragma unroll
        for (int c=0;c<16;c++){
            float r = sdb[c];
            #pragma unroll
            for (int k=0;k<16;k++) r += xv[k]*sdt[k*16+c];
            v[c] = fin(ag[c] + r);
        }
        ln_act16(v, s1g, s1b, dupd);
    }
    {
        const float* ag = agg_tt + i*16;
        float v[16];
        #pragma unroll
        for (int c=0;c<16;c++){
            float r = stb[c];
            #pragma unroll
            for (int k=0;k<16;k++) r += xv[k]*stt[k*16+c];
            v[c] = fin(ag[c] + r);
        }
        ln_act16(v, s2g, s2b, tupd);
    }
    #pragma unroll
    for (int j=0;j<48;j++) vals[j] = fin(vals[j]);
    #pragma unroll
    for (int g=0; g<16; g++){
        if (i == sptr[g]){
            for (int j=0;j<48;j++) stf(out, g*96+j, vals[j], isbf);
        }
    }
    int gi = b_tasks[i];
    int g0 = b_tasks[blockIdx.x*256];
    if (gi != g0) s_nonuni = 1;
    __syncthreads();
    if (s_nonuni){
        for (int j=0;j<48;j++) atomicAdd(&pool_sums[gi*48+j], vals[j]);
        atomicAdd(&pool_cnt[gi], 1.f);
    } else {
        int lane = t & 63, wid = t >> 6;
        #pragma unroll
        for (int j=0;j<48;j++){
            float v = vals[j];
            v += __shfl_down(v, 32);
            v += __shfl_down(v, 16);
            v += __shfl_down(v, 8);
            v += __shfl_down(v, 4);
            v += __shfl_down(v, 2);
            v += __shfl_down(v, 1);
            if (lane==0) swave[wid*48+j] = v;
        }
        __syncthreads();
        if (t < 48){
            float s = swave[t] + swave[48+t] + swave[96+t] + swave[144+t];
            atomicAdd(&pool_sums[g0*48+t], s);
        }
        if (t == 0) atomicAdd(&pool_cnt[g0], 256.f);
    }
}

__global__ void finish_kernel(const float* __restrict__ sums, const float* __restrict__ cnt,
                              void* __restrict__ out, const int* __restrict__ flag)
{
    int t = threadIdx.x;
    if (t >= 768) return;
    int g = t/48, c = t - g*48;
    stf(out, g*96+48+c, fin(sums[g*48+c]/fmaxf(cnt[g],1.f)), *flag);
}

extern "C" void kernel_launch(void* const* d_in, const int* in_sizes, int n_in,
                              void* d_out, int out_size, void* d_ws, size_t ws_size,
                              hipStream_t stream)
{
    const void* x_tasks  = d_in[0];
    const void* x_data   = d_in[1];
    const void* stem_t_W = d_in[2];
    const void* stem_t_b = d_in[3];
    const void* stem_d_W = d_in[4];
    const void* stem_d_b = d_in[5];
    const void* ln_t_g   = d_in[6];
    const void* ln_t_b   = d_in[7];
    const void* ln_d_g   = d_in[8];
    const void* ln_d_b   = d_in[9];
    const void* dt_Wl    = d_in[10];
    const void* dt_Wr    = d_in[11];
    const void* dt_att   = d_in[12];
    const void* dt_res   = d_in[13];
    const void* dt_bias  = d_in[14];
    const void* tt_Wl    = d_in[15];
    const void* tt_Wr    = d_in[16];
    const void* tt_att   = d_in[17];
    const void* tt_res   = d_in[18];
    const void* tt_bias  = d_in[19];
    const void* ln1_g    = d_in[20];
    const void* ln1_b    = d_in[21];
    const void* ln2_g    = d_in[22];
    const void* ln2_b    = d_in[23];
    const int*  ei_dt    = (const int*)d_in[24];
    const int*  mask_dt  = (const int*)d_in[25];
    const int*  ei_tt    = (const int*)d_in[26];
    const int*  b_tasks  = (const int*)d_in[27];
    const int*  ptrg     = (const int*)d_in[28];

    char* w = (char*)d_ws;
    const size_t MB = 1ull<<20;
    float*    xt        = (float*)(w);              // 16 MB  [NT,16]
    float*    xl_dt     = (float*)(w + 16*MB);      // 32 MB  [ND,32]
    float*    xl_tt     = (float*)(w + 48*MB);      // 32 MB  [NT,32]
    float*    agg       = (float*)(w + 80*MB);      // 32 MB  [NSLOT,16]
    unsigned* ebuf      = (unsigned*)(w + 112*MB);  // 12 MB (NBKT*BCAP) + 1 MB slack
    int*      bktCur    = (int*)  (w + 125*MB);     // 4 KB
    float*    pool_sums = (float*)(w + 125*MB + 8192);
    float*    pool_cnt  = (float*)(w + 125*MB + 12288);
    int*      flag      = (int*)  (w + 125*MB + 16384);

    detect_kernel<<<1, 256, 0, stream>>>((const unsigned*)x_tasks, flag);
    init_cursors_kernel<<<(NBKT+255)/256, 256, 0, stream>>>(bktCur);
    // zero pool accumulators only (flag is set by detect_kernel after this region)
    hipMemsetAsync(w + 125*MB + 8192, 0, 8192, stream);

    // stems
    stem_task_kernel<<<NT/256, 256, 0, stream>>>(x_tasks, stem_t_W, stem_t_b, ln_t_g, ln_t_b,
                                                 tt_Wl, xt, xl_tt, flag);
    stem_data_transform_kernel<<<ND/256, 256, 0, stream>>>(x_data, stem_d_W, stem_d_b,
                                                           ln_d_g, ln_d_b, dt_Wl, xl_dt, flag);

    // phase 1: coarse bucket scatter (both graphs)
    bucket_scatter_kernel<<<NBLK1, 256, 0, stream>>>(ei_dt, mask_dt, ei_tt, bktCur, ebuf);

    // phase 2: per-bucket LDS CSR + aggregation (both graphs)
    bucket_aggregate_kernel<<<NBKT, 256, 0, stream>>>(bktCur, ebuf, xt, xl_dt, xl_tt,
        dt_Wr, tt_Wr, dt_att, tt_att, agg, flag);

    // fuse + pool + output
    fuse_pool_kernel<<<NT/256, 256, 0, stream>>>(xt, agg, agg + (long)NT*16,
        dt_res, dt_bias, tt_res, tt_bias, ln1_g, ln1_b, ln2_g, ln2_b,
        b_tasks, ptrg, pool_sums, pool_cnt, d_out, flag);
    finish_kernel<<<1, 768, 0, stream>>>(pool_sums, pool_cnt, d_out, flag);
}